// Round 2
// baseline (1939.747 us; speedup 1.0000x reference)
//
#include <hip/hip_runtime.h>
#include <cstdint>

#define NH 12
#define HD 64
#define NSEQ 2048
#define CDIM 768
#define NB 2

// ---------------------------------------------------------------------------
// Kernel 1: QKV = x @ qkv_w^T with f64 accumulation.
// Q [b,h,n,d] (double), Kt [b,h,d,n] (double), V [b,h,n,d] (float)
// ---------------------------------------------------------------------------
__global__ __launch_bounds__(256) void qkv_gemm(const float* __restrict__ x,
                                                const float* __restrict__ w,
                                                double* __restrict__ Q,
                                                double* __restrict__ Kt,
                                                float* __restrict__ V) {
    __shared__ double As[16][64];
    __shared__ double Bs[16][64];
    const int tid = threadIdx.x;
    const int bm = blockIdx.y * 64;   // row block (M=4096)
    const int bn = blockIdx.x * 64;   // col block (N=2304)
    const int lm = tid >> 2;          // 0..63
    const int lk = (tid & 3) << 2;    // 0,4,8,12
    const int tx = tid & 15, ty = tid >> 4;

    double acc[4][4] = {};
    for (int k0 = 0; k0 < CDIM; k0 += 16) {
        float4 av = *reinterpret_cast<const float4*>(&x[(bm + lm) * CDIM + k0 + lk]);
        float4 bv = *reinterpret_cast<const float4*>(&w[(bn + lm) * CDIM + k0 + lk]);
        As[lk + 0][lm] = (double)av.x; As[lk + 1][lm] = (double)av.y;
        As[lk + 2][lm] = (double)av.z; As[lk + 3][lm] = (double)av.w;
        Bs[lk + 0][lm] = (double)bv.x; Bs[lk + 1][lm] = (double)bv.y;
        Bs[lk + 2][lm] = (double)bv.z; Bs[lk + 3][lm] = (double)bv.w;
        __syncthreads();
#pragma unroll
        for (int k = 0; k < 16; ++k) {
            double aa[4], bb[4];
#pragma unroll
            for (int i = 0; i < 4; ++i) { aa[i] = As[k][ty * 4 + i]; bb[i] = Bs[k][tx * 4 + i]; }
#pragma unroll
            for (int i = 0; i < 4; ++i)
#pragma unroll
                for (int j = 0; j < 4; ++j) acc[i][j] += aa[i] * bb[j];
        }
        __syncthreads();
    }
    // scatter: whole block shares t (q/k/v) and head hh since 64 | 768
    const int t  = bn / CDIM;
    const int hh = (bn % CDIM) >> 6;
    const int b  = bm >> 11;               // batch (64 | 2048)
    const int bh = b * NH + hh;
#pragma unroll
    for (int i = 0; i < 4; ++i) {
        int r = bm + ty * 4 + i;
        int n = r & (NSEQ - 1);
        if (t == 0) {
#pragma unroll
            for (int j = 0; j < 4; ++j)
                Q[((size_t)bh * NSEQ + n) * HD + tx * 4 + j] = acc[i][j];
        } else if (t == 2) {
            float4 v4 = make_float4((float)acc[i][0], (float)acc[i][1],
                                    (float)acc[i][2], (float)acc[i][3]);
            *reinterpret_cast<float4*>(&V[((size_t)bh * NSEQ + n) * HD + tx * 4]) = v4;
        } else {
#pragma unroll
            for (int j = 0; j < 4; ++j) {
                int d = tx * 4 + j;
                Kt[((size_t)bh * HD + d) * NSEQ + n] = acc[i][j];
            }
        }
    }
}

// ---------------------------------------------------------------------------
// Kernel 2: per-row f64 scores -> top-k -> top-p -> softmax -> sparse PV
// block = 256 threads (4 waves), handles 4 rows of one (b,h); wave g owns row g
// ---------------------------------------------------------------------------
__device__ inline unsigned long long d2key(double f) {
    unsigned long long u = (unsigned long long)__double_as_longlong(f);
    return u ^ (unsigned long long)(((long long)u >> 63) | (long long)0x8000000000000000ull);
}
__device__ inline double key2d(unsigned long long k) {
    unsigned long long mask = ((long long)k < 0) ? 0x8000000000000000ull : 0xFFFFFFFFFFFFFFFFull;
    return __longlong_as_double((long long)(k ^ mask));
}

__global__ __launch_bounds__(256) void attn_kernel(const double* __restrict__ Q,
                                                   const double* __restrict__ Kt,
                                                   const float* __restrict__ V,
                                                   const float* __restrict__ temp,
                                                   const int* __restrict__ topk_p,
                                                   float* __restrict__ AO) {
    __shared__ double qs[4][HD];
    __shared__ double scores[4][NSEQ];
    __shared__ unsigned long long klist[4][64];
    __shared__ unsigned short ilist[4][64];
    __shared__ int cnt[4];

    const int tid  = threadIdx.x;
    const int bh   = blockIdx.x >> 9;          // 512 row-groups per (b,h)
    const int g0   = (blockIdx.x & 511) << 2;  // first row of this block
    const int lane = tid & 63;
    const int wv   = tid >> 6;                 // wave id = row within group

    const double scale = 0.125 * (double)temp[0];
    int TK = *topk_p;
    if (TK > 64) TK = 64;
    if (TK < 1)  TK = 1;

    if (tid < 4) cnt[tid] = 0;
    klist[wv][lane] = 0ull;
    ilist[wv][lane] = 0;

    // load q rows, pre-scaled (f64)
    {
        int g = tid >> 6, d = tid & 63;
        qs[g][d] = Q[((size_t)bh * NSEQ + g0 + g) * HD + d] * scale;
    }
    __syncthreads();

    // ---- phase 2: scores[g][m] = q_g . K_m  in f64; thread owns 8 columns
    const double* kb = Kt + (size_t)bh * HD * NSEQ;
    const int m0 = tid * 8;
    double acc[4][8] = {};
#pragma unroll 4
    for (int d = 0; d < HD; ++d) {
        const double* kr = kb + (size_t)d * NSEQ + m0;
        double2 k01 = *reinterpret_cast<const double2*>(kr + 0);
        double2 k23 = *reinterpret_cast<const double2*>(kr + 2);
        double2 k45 = *reinterpret_cast<const double2*>(kr + 4);
        double2 k67 = *reinterpret_cast<const double2*>(kr + 6);
        double kv[8] = {k01.x, k01.y, k23.x, k23.y, k45.x, k45.y, k67.x, k67.y};
        double q0 = qs[0][d], q1 = qs[1][d], q2 = qs[2][d], q3 = qs[3][d];
#pragma unroll
        for (int c = 0; c < 8; ++c) {
            acc[0][c] += q0 * kv[c];
            acc[1][c] += q1 * kv[c];
            acc[2][c] += q2 * kv[c];
            acc[3][c] += q3 * kv[c];
        }
    }
#pragma unroll
    for (int g = 0; g < 4; ++g)
#pragma unroll
        for (int c = 0; c < 8; c += 2) {
            double2 s2; s2.x = acc[g][c]; s2.y = acc[g][c + 1];
            *reinterpret_cast<double2*>(&scores[g][m0 + c]) = s2;
        }
    __syncthreads();

    // ---- phase 3 (per wave, row g = wv)
    const int g = wv;
    const int row = g0 + g;

    // keys in registers: keys[i] <-> column m = i*64 + lane
    unsigned long long keys[32];
#pragma unroll
    for (int i = 0; i < 32; ++i) keys[i] = d2key(scores[g][i * 64 + lane]);

    // binary search the TK-th largest key (largest key with count(>=key) >= TK)
    unsigned long long lo = 0ull, hi = 0xFFFFFFFFFFFFFFFFull;
    while (lo < hi) {
        unsigned long long d = hi - lo;
        unsigned long long mid = lo + (d >> 1) + (d & 1ull);
        int c = 0;
#pragma unroll
        for (int i = 0; i < 32; ++i) c += (keys[i] >= mid) ? 1 : 0;
#pragma unroll
        for (int off = 32; off > 0; off >>= 1) c += __shfl_xor(c, off);
        if (c >= TK) lo = mid; else hi = mid - 1ull;
    }

    // compact survivors (key >= lo) into per-row list
#pragma unroll
    for (int i = 0; i < 32; ++i) {
        if (keys[i] >= lo) {
            int slot = atomicAdd(&cnt[g], 1);
            if (slot < 64) {
                klist[g][slot] = keys[i];
                ilist[g][slot] = (unsigned short)(i * 64 + lane);
            }
        }
    }
    int cfin = 0;
#pragma unroll
    for (int i = 0; i < 32; ++i) cfin += (keys[i] >= lo) ? 1 : 0;
#pragma unroll
    for (int off = 32; off > 0; off >>= 1) cfin += __shfl_xor(cfin, off);
    int nvalid = min(cfin, 64);

    // drain this wave's LDS ops before reading the compacted list
    asm volatile("s_waitcnt lgkmcnt(0)" ::: "memory");

    unsigned long long kk = klist[g][lane];
    unsigned mi = (unsigned)ilist[g][lane];

    // bitonic sort across 64 lanes: ascending in t = ~key  (== descending by key)
    unsigned long long t = ~kk;
#pragma unroll
    for (int k = 2; k <= 64; k <<= 1) {
#pragma unroll
        for (int j = k >> 1; j > 0; j >>= 1) {
            unsigned long long ot = __shfl_xor(t, j);
            unsigned om = __shfl_xor(mi, j);
            bool dir = (lane & k) != 0;
            bool lower = (lane & j) == 0;
            bool takeMin = (lower != dir);
            bool less = t < ot;
            bool self = takeMin ? less : !less;
            t  = self ? t : ot;
            mi = self ? mi : om;
        }
    }
    kk = ~t;  // lane l holds l-th largest key

    bool valid = lane < nvalid;
    double a = valid ? key2d(kk) : 0.0;
    double amax = __shfl(a, 0);
    double s = valid ? exp(a - amax) : 0.0;

    // inclusive prefix sum of s across the wave (f64)
    double ps = s;
#pragma unroll
    for (int off = 1; off < 64; off <<= 1) {
        double tt = __shfl_up(ps, off);
        if (lane >= off) ps += tt;
    }
    double S = __shfl(ps, 63);
    double cumprev = (ps - s) / S;           // cumulative prob BEFORE this entry
    bool keep = valid && ((lane == 0) || (cumprev <= 0.9));
    double sk = keep ? s : 0.0;
    double S2 = sk;
#pragma unroll
    for (int off = 32; off > 0; off >>= 1) S2 += __shfl_xor(S2, off);
    float p = (float)(keep ? (s / S2) : 0.0);

    unsigned long long bal = __ballot(keep);
    int nk = __popcll(bal);                 // kept set is a prefix of sorted order

    // sparse PV: out[d] = sum_i p_i * V[m_i][d]   (f32)
    const float* vb = V + (size_t)bh * NSEQ * HD;
    float o = 0.f;
    for (int i = 0; i < nk; ++i) {
        float pi = __shfl(p, i);
        int midx = __shfl((int)mi, i);
        o += pi * vb[(size_t)midx * HD + lane];
    }
    const int b = bh / NH, hh = bh % NH;
    AO[((size_t)b * NSEQ + row) * CDIM + hh * HD + lane] = o;
}

// ---------------------------------------------------------------------------
// Kernel 3: out = AO @ proj_w^T + proj_b   (f32)
// ---------------------------------------------------------------------------
__global__ __launch_bounds__(256) void proj_gemm(const float* __restrict__ A,
                                                 const float* __restrict__ w,
                                                 const float* __restrict__ bias,
                                                 float* __restrict__ out) {
    __shared__ float As[16][64];
    __shared__ float Bs[16][64];
    const int tid = threadIdx.x;
    const int bm = blockIdx.y * 64;
    const int bn = blockIdx.x * 64;
    const int lm = tid >> 2;
    const int lk = (tid & 3) << 2;
    const int tx = tid & 15, ty = tid >> 4;

    float acc[4][4] = {};
    for (int k0 = 0; k0 < CDIM; k0 += 16) {
        float4 av = *reinterpret_cast<const float4*>(&A[(bm + lm) * CDIM + k0 + lk]);
        float4 bv = *reinterpret_cast<const float4*>(&w[(bn + lm) * CDIM + k0 + lk]);
        As[lk + 0][lm] = av.x; As[lk + 1][lm] = av.y; As[lk + 2][lm] = av.z; As[lk + 3][lm] = av.w;
        Bs[lk + 0][lm] = bv.x; Bs[lk + 1][lm] = bv.y; Bs[lk + 2][lm] = bv.z; Bs[lk + 3][lm] = bv.w;
        __syncthreads();
#pragma unroll
        for (int k = 0; k < 16; ++k) {
            float4 a4 = *reinterpret_cast<const float4*>(&As[k][ty * 4]);
            float4 b4 = *reinterpret_cast<const float4*>(&Bs[k][tx * 4]);
            float aa[4] = {a4.x, a4.y, a4.z, a4.w};
            float bb[4] = {b4.x, b4.y, b4.z, b4.w};
#pragma unroll
            for (int i = 0; i < 4; ++i)
#pragma unroll
                for (int j = 0; j < 4; ++j) acc[i][j] += aa[i] * bb[j];
        }
        __syncthreads();
    }
    float4 bv = *reinterpret_cast<const float4*>(&bias[bn + tx * 4]);
#pragma unroll
    for (int i = 0; i < 4; ++i) {
        int r = bm + ty * 4 + i;
        float4 v4 = make_float4(acc[i][0] + bv.x, acc[i][1] + bv.y,
                                acc[i][2] + bv.z, acc[i][3] + bv.w);
        *reinterpret_cast<float4*>(&out[(size_t)r * CDIM + bn + tx * 4]) = v4;
    }
}

// ---------------------------------------------------------------------------
extern "C" void kernel_launch(void* const* d_in, const int* in_sizes, int n_in,
                              void* d_out, int out_size, void* d_ws, size_t ws_size,
                              hipStream_t stream) {
    const float* x      = (const float*)d_in[0];
    const float* qkv_w  = (const float*)d_in[1];
    const float* proj_w = (const float*)d_in[2];
    const float* proj_b = (const float*)d_in[3];
    const float* temp   = (const float*)d_in[4];
    const int*   topk   = (const int*)d_in[5];
    float* out = (float*)d_out;

    const size_t HSZ = (size_t)NB * NH * NSEQ * HD;  // 3,145,728 elements per tensor
    double* Q  = (double*)d_ws;
    double* Kt = Q + HSZ;
    float*  V  = (float*)(Kt + HSZ);
    float*  AO = V + HSZ;

    qkv_gemm<<<dim3(36, 64), 256, 0, stream>>>(x, qkv_w, Q, Kt, V);
    attn_kernel<<<dim3(NB * NH * (NSEQ / 4)), 256, 0, stream>>>(Q, Kt, V, temp, topk, AO);
    proj_gemm<<<dim3(12, 64), 256, 0, stream>>>(AO, proj_w, proj_b, out);
}

// Round 3
// 1134.068 us; speedup vs baseline: 1.7104x; 1.7104x over previous
//
#include <hip/hip_runtime.h>
#include <cstdint>

#define NH 12
#define HD 64
#define NSEQ 2048
#define CDIM 768
#define NB 2

// ---------------------------------------------------------------------------
// Kernel 1: QKV = x @ qkv_w^T with f64 accumulation.
// Q64 [bh][n][d] f64 ; K64 [bh][m][d] f64 ; Kt32 [bh][d][m] f32 ; V [bh][n][d] f32
// ---------------------------------------------------------------------------
__global__ __launch_bounds__(256) void qkv_gemm(const float* __restrict__ x,
                                                const float* __restrict__ w,
                                                double* __restrict__ Q,
                                                double* __restrict__ K64,
                                                float* __restrict__ Kt32,
                                                float* __restrict__ V) {
    __shared__ double As[16][64];
    __shared__ double Bs[16][64];
    const int tid = threadIdx.x;
    const int bm = blockIdx.y * 64;   // row block (M=4096)
    const int bn = blockIdx.x * 64;   // col block (N=2304)
    const int lm = tid >> 2;          // 0..63
    const int lk = (tid & 3) << 2;    // 0,4,8,12
    const int tx = tid & 15, ty = tid >> 4;

    double acc[4][4] = {};
    for (int k0 = 0; k0 < CDIM; k0 += 16) {
        float4 av = *reinterpret_cast<const float4*>(&x[(bm + lm) * CDIM + k0 + lk]);
        float4 bv = *reinterpret_cast<const float4*>(&w[(bn + lm) * CDIM + k0 + lk]);
        As[lk + 0][lm] = (double)av.x; As[lk + 1][lm] = (double)av.y;
        As[lk + 2][lm] = (double)av.z; As[lk + 3][lm] = (double)av.w;
        Bs[lk + 0][lm] = (double)bv.x; Bs[lk + 1][lm] = (double)bv.y;
        Bs[lk + 2][lm] = (double)bv.z; Bs[lk + 3][lm] = (double)bv.w;
        __syncthreads();
#pragma unroll
        for (int k = 0; k < 16; ++k) {
            double aa[4], bb[4];
#pragma unroll
            for (int i = 0; i < 4; ++i) { aa[i] = As[k][ty * 4 + i]; bb[i] = Bs[k][tx * 4 + i]; }
#pragma unroll
            for (int i = 0; i < 4; ++i)
#pragma unroll
                for (int j = 0; j < 4; ++j) acc[i][j] += aa[i] * bb[j];
        }
        __syncthreads();
    }
    const int t  = bn / CDIM;
    const int hh = (bn % CDIM) >> 6;
    const int b  = bm >> 11;
    const int bh = b * NH + hh;
#pragma unroll
    for (int i = 0; i < 4; ++i) {
        int r = bm + ty * 4 + i;
        int n = r & (NSEQ - 1);
        if (t == 0) {
#pragma unroll
            for (int j = 0; j < 4; ++j)
                Q[((size_t)bh * NSEQ + n) * HD + tx * 4 + j] = acc[i][j];
        } else if (t == 2) {
            float4 v4 = make_float4((float)acc[i][0], (float)acc[i][1],
                                    (float)acc[i][2], (float)acc[i][3]);
            *reinterpret_cast<float4*>(&V[((size_t)bh * NSEQ + n) * HD + tx * 4]) = v4;
        } else {
#pragma unroll
            for (int j = 0; j < 4; ++j) {
                int d = tx * 4 + j;
                K64[((size_t)bh * NSEQ + n) * HD + d] = acc[i][j];
                Kt32[((size_t)bh * HD + d) * NSEQ + n] = (float)acc[i][j];
            }
        }
    }
}

// ---------------------------------------------------------------------------
// Kernel 2: f32 bulk scores -> u16-key candidate select -> f64 rescore of
// candidates -> 128-wide bitonic sort -> exact f64 softmax/top-p -> sparse PV
// block = 256 threads (4 waves), 8 rows of one (b,h); wave w does rows w, w+4
// ---------------------------------------------------------------------------
__device__ inline unsigned long long d2key(double f) {
    unsigned long long u = (unsigned long long)__double_as_longlong(f);
    return u ^ (unsigned long long)(((long long)u >> 63) | (long long)0x8000000000000000ull);
}
__device__ inline double key2d(unsigned long long k) {
    unsigned long long mask = ((long long)k < 0) ? 0x8000000000000000ull : 0xFFFFFFFFFFFFFFFFull;
    return __longlong_as_double((long long)(k ^ mask));
}
// pack two f32 scores into two monotone u16 keys (truncated monotone u32 map)
__device__ inline unsigned kp(float a, float b) {
    unsigned ua = __float_as_uint(a);
    ua ^= (unsigned)(((int)ua >> 31) | 0x80000000);
    unsigned ub = __float_as_uint(b);
    ub ^= (unsigned)(((int)ub >> 31) | 0x80000000);
    return (ua >> 16) | (ub & 0xFFFF0000u);
}

__global__ __launch_bounds__(256, 4) void attn_kernel(const double* __restrict__ Q,
                                                      const double* __restrict__ K64,
                                                      const float* __restrict__ Kt32,
                                                      const float* __restrict__ V,
                                                      const float* __restrict__ temp,
                                                      const int* __restrict__ topk_p,
                                                      float* __restrict__ AO) {
    __shared__ unsigned short sk[8][NSEQ];   // 32 KB u16 keys
    __shared__ float qs32f[HD][8];           // [d][r] f32 scaled q
    __shared__ int cand[8][128];
    __shared__ int cnt8[8];

    const int tid  = threadIdx.x;
    const int bh   = blockIdx.x >> 8;          // 256 groups of 8 rows per (b,h)
    const int g0   = (blockIdx.x & 255) << 3;  // first row
    const int lane = tid & 63;
    const int wv   = tid >> 6;

    const double scale = 0.125 * (double)temp[0];
    int TK = *topk_p;
    if (TK > 64) TK = 64;
    if (TK < 1)  TK = 1;

    if (tid < 8) cnt8[tid] = 0;
    // load q rows (scaled) as f32
    {
        int idx = tid;
#pragma unroll
        for (int it = 0; it < 2; ++it, idx += 256) {
            int r = idx >> 6, d = idx & 63;
            double q = Q[((size_t)bh * NSEQ + g0 + r) * HD + d] * scale;
            qs32f[d][r] = (float)q;
        }
    }
    __syncthreads();

    // ---- phase 2: f32 scores, thread owns 8 consecutive columns for all 8 rows
    const float* kb = Kt32 + (size_t)bh * HD * NSEQ;
    const int m0 = tid * 8;
    float acc[8][8] = {};
#pragma unroll 2
    for (int d = 0; d < HD; ++d) {
        const float* kr = kb + (size_t)d * NSEQ + m0;
        float4 k0 = *reinterpret_cast<const float4*>(kr);
        float4 k1 = *reinterpret_cast<const float4*>(kr + 4);
        float kv[8] = {k0.x, k0.y, k0.z, k0.w, k1.x, k1.y, k1.z, k1.w};
        float4 qA = *reinterpret_cast<const float4*>(&qs32f[d][0]);
        float4 qB = *reinterpret_cast<const float4*>(&qs32f[d][4]);
        float qa[8] = {qA.x, qA.y, qA.z, qA.w, qB.x, qB.y, qB.z, qB.w};
#pragma unroll
        for (int r = 0; r < 8; ++r)
#pragma unroll
            for (int c = 0; c < 8; ++c) acc[r][c] = fmaf(qa[r], kv[c], acc[r][c]);
    }
#pragma unroll
    for (int r = 0; r < 8; ++r) {
        uint4 pkv;
        pkv.x = kp(acc[r][0], acc[r][1]);
        pkv.y = kp(acc[r][2], acc[r][3]);
        pkv.z = kp(acc[r][4], acc[r][5]);
        pkv.w = kp(acc[r][6], acc[r][7]);
        *reinterpret_cast<uint4*>(&sk[r][m0]) = pkv;
    }
    __syncthreads();

    // ---- phase 3: per wave, two rows
    const double* qbase = Q + (size_t)bh * NSEQ * HD;
    const double* kk64  = K64 + (size_t)bh * NSEQ * HD;
    const float*  vb    = V + (size_t)bh * NSEQ * HD;

    for (int rr = 0; rr < 2; ++rr) {
        const int r = wv + rr * 4;
        const int row = g0 + r;

        int k32[32];
#pragma unroll
        for (int i = 0; i < 32; ++i) k32[i] = sk[r][i * 64 + lane];

        // early-stopped binary search on u16 keys: largest lo with count(>=lo) >= TK,
        // stop once that count <= 96
        int lo = 0, hi = 65535, clo = NSEQ;
        while (lo < hi && clo > 96) {
            int mid = (lo + hi + 1) >> 1;
            int c = 0;
#pragma unroll
            for (int i = 0; i < 32; ++i) c += (k32[i] >= mid) ? 1 : 0;
#pragma unroll
            for (int off = 32; off > 0; off >>= 1) c += __shfl_xor(c, off);
            if (c >= TK) { lo = mid; clo = c; } else hi = mid - 1;
        }
        int thr = lo >= 2 ? lo - 2 : 0;   // 2-ulp margin covers f32-dot + trunc error

        // compact candidate column indices
#pragma unroll
        for (int i = 0; i < 32; ++i) {
            if (k32[i] >= thr) {
                int slot = atomicAdd(&cnt8[r], 1);
                if (slot < 128) cand[r][slot] = i * 64 + lane;
            }
        }
        asm volatile("s_waitcnt lgkmcnt(0)" ::: "memory");
        int ncand = cnt8[r];
        if (ncand > 128) ncand = 128;

        // f64 rescore (bit-identical to reference chain: q*scale then d-seq fma)
        int c2 = 64 + lane;
        int m1 = cand[r][min(lane, ncand - 1)];
        int m2 = cand[r][min(c2, ncand - 1)];
        const double* qrow = qbase + (size_t)row * HD;
        const double* k1p = kk64 + (size_t)m1 * HD;
        const double* k2p = kk64 + (size_t)m2 * HD;
        double a1 = 0.0, a2 = 0.0;
#pragma unroll 4
        for (int d = 0; d < HD; ++d) {
            double qd = qrow[d] * scale;
            a1 = fma(qd, k1p[d], a1);
            a2 = fma(qd, k2p[d], a2);
        }
        unsigned long long kk1 = (lane < ncand) ? d2key(a1) : 0ull;
        unsigned long long kk2 = (c2 < ncand) ? d2key(a2) : 0ull;

        // bitonic sort of 128 (2/lane), ascending in t=~key == descending by key
        unsigned long long t0 = ~kk1, t1 = ~kk2;
        unsigned q0 = (unsigned)m1, q1 = (unsigned)m2;
#pragma unroll
        for (int k = 2; k <= 64; k <<= 1) {
#pragma unroll
            for (int j = k >> 1; j > 0; j >>= 1) {
                {
                    unsigned long long ot = __shfl_xor(t0, j);
                    unsigned om = __shfl_xor(q0, j);
                    bool dir = (lane & k) != 0;
                    bool lower = (lane & j) == 0;
                    bool takeMin = (lower != dir);
                    bool less = t0 < ot;
                    bool self = (takeMin == less);
                    t0 = self ? t0 : ot; q0 = self ? q0 : om;
                }
                {
                    unsigned long long ot = __shfl_xor(t1, j);
                    unsigned om = __shfl_xor(q1, j);
                    bool dir = (k == 64) ? true : ((lane & k) != 0);
                    bool lower = (lane & j) == 0;
                    bool takeMin = (lower != dir);
                    bool less = t1 < ot;
                    bool self = (takeMin == less);
                    t1 = self ? t1 : ot; q1 = self ? q1 : om;
                }
            }
        }
        {   // k=128, j=64: cross-slot local exchange (ascending: slot0 keeps min)
            bool sw = t1 < t0;
            unsigned long long na = sw ? t1 : t0, nb = sw ? t0 : t1;
            unsigned ma = sw ? q1 : q0, mb = sw ? q0 : q1;
            t0 = na; t1 = nb; q0 = ma; q1 = mb;
        }
#pragma unroll
        for (int j = 32; j > 0; j >>= 1) {
            {
                unsigned long long ot = __shfl_xor(t0, j);
                unsigned om = __shfl_xor(q0, j);
                bool lower = (lane & j) == 0;
                bool less = t0 < ot;
                bool self = (lower == less);
                t0 = self ? t0 : ot; q0 = self ? q0 : om;
            }
            {
                unsigned long long ot = __shfl_xor(t1, j);
                unsigned om = __shfl_xor(q1, j);
                bool lower = (lane & j) == 0;
                bool less = t1 < ot;
                bool self = (lower == less);
                t1 = self ? t1 : ot; q1 = self ? q1 : om;
            }
        }
        // lane l of slot0 = l-th largest by exact f64 key
        unsigned long long kk = ~t0;
        bool valid = lane < TK;
        double a = valid ? key2d(kk) : 0.0;
        double amax = __shfl(a, 0);
        double s = valid ? exp(a - amax) : 0.0;

        double ps = s;
#pragma unroll
        for (int off = 1; off < 64; off <<= 1) {
            double tt = __shfl_up(ps, off);
            if (lane >= off) ps += tt;
        }
        double S = __shfl(ps, 63);
        double cumprev = (ps - s) / S;
        bool keep = valid && ((lane == 0) || (cumprev <= 0.9));
        double sk2 = keep ? s : 0.0;
        double S2 = sk2;
#pragma unroll
        for (int off = 32; off > 0; off >>= 1) S2 += __shfl_xor(S2, off);
        float p = (float)(keep ? (s / S2) : 0.0);

        unsigned long long bal = __ballot(keep);
        int nk = __popcll(bal);

        float o = 0.f;
        for (int i = 0; i < nk; ++i) {
            float pi = __shfl(p, i);
            int midx = __shfl((int)q0, i);
            o += pi * vb[(size_t)midx * HD + lane];
        }
        const int b = bh / NH, hh = bh % NH;
        AO[((size_t)b * NSEQ + row) * CDIM + hh * HD + lane] = o;
    }
}

// ---------------------------------------------------------------------------
// Kernel 3: out = AO @ proj_w^T + proj_b   (f32)
// ---------------------------------------------------------------------------
__global__ __launch_bounds__(256) void proj_gemm(const float* __restrict__ A,
                                                 const float* __restrict__ w,
                                                 const float* __restrict__ bias,
                                                 float* __restrict__ out) {
    __shared__ float As[16][64];
    __shared__ float Bs[16][64];
    const int tid = threadIdx.x;
    const int bm = blockIdx.y * 64;
    const int bn = blockIdx.x * 64;
    const int lm = tid >> 2;
    const int lk = (tid & 3) << 2;
    const int tx = tid & 15, ty = tid >> 4;

    float acc[4][4] = {};
    for (int k0 = 0; k0 < CDIM; k0 += 16) {
        float4 av = *reinterpret_cast<const float4*>(&A[(bm + lm) * CDIM + k0 + lk]);
        float4 bv = *reinterpret_cast<const float4*>(&w[(bn + lm) * CDIM + k0 + lk]);
        As[lk + 0][lm] = av.x; As[lk + 1][lm] = av.y; As[lk + 2][lm] = av.z; As[lk + 3][lm] = av.w;
        Bs[lk + 0][lm] = bv.x; Bs[lk + 1][lm] = bv.y; Bs[lk + 2][lm] = bv.z; Bs[lk + 3][lm] = bv.w;
        __syncthreads();
#pragma unroll
        for (int k = 0; k < 16; ++k) {
            float4 a4 = *reinterpret_cast<const float4*>(&As[k][ty * 4]);
            float4 b4 = *reinterpret_cast<const float4*>(&Bs[k][tx * 4]);
            float aa[4] = {a4.x, a4.y, a4.z, a4.w};
            float bb[4] = {b4.x, b4.y, b4.z, b4.w};
#pragma unroll
            for (int i = 0; i < 4; ++i)
#pragma unroll
                for (int j = 0; j < 4; ++j) acc[i][j] += aa[i] * bb[j];
        }
        __syncthreads();
    }
    float4 bv = *reinterpret_cast<const float4*>(&bias[bn + tx * 4]);
#pragma unroll
    for (int i = 0; i < 4; ++i) {
        int r = bm + ty * 4 + i;
        float4 v4 = make_float4(acc[i][0] + bv.x, acc[i][1] + bv.y,
                                acc[i][2] + bv.z, acc[i][3] + bv.w);
        *reinterpret_cast<float4*>(&out[(size_t)r * CDIM + bn + tx * 4]) = v4;
    }
}

// ---------------------------------------------------------------------------
extern "C" void kernel_launch(void* const* d_in, const int* in_sizes, int n_in,
                              void* d_out, int out_size, void* d_ws, size_t ws_size,
                              hipStream_t stream) {
    const float* x      = (const float*)d_in[0];
    const float* qkv_w  = (const float*)d_in[1];
    const float* proj_w = (const float*)d_in[2];
    const float* proj_b = (const float*)d_in[3];
    const float* temp   = (const float*)d_in[4];
    const int*   topk   = (const int*)d_in[5];
    float* out = (float*)d_out;

    const size_t HSZ = (size_t)NB * NH * NSEQ * HD;  // 3,145,728 elements
    double* Q64  = (double*)d_ws;          // 24 MB
    double* K64  = Q64 + HSZ;              // 24 MB
    float*  Kt32 = (float*)(K64 + HSZ);    // 12 MB
    float*  V    = Kt32 + HSZ;             // 12 MB
    float*  AO   = V + HSZ;                // 12 MB

    qkv_gemm<<<dim3(36, 64), 256, 0, stream>>>(x, qkv_w, Q64, K64, Kt32, V);
    attn_kernel<<<dim3(NB * NH * (NSEQ / 8)), 256, 0, stream>>>(Q64, K64, Kt32, V, temp, topk, AO);
    proj_gemm<<<dim3(12, 64), 256, 0, stream>>>(AO, proj_w, proj_b, out);
}

// Round 4
// 1089.775 us; speedup vs baseline: 1.7800x; 1.0406x over previous
//
#include <hip/hip_runtime.h>
#include <cstdint>

#define NH 12
#define HD 64
#define NSEQ 2048
#define CDIM 768
#define NB 2

// ---------------------------------------------------------------------------
// Kernel 1: QKV = x @ qkv_w^T with f64 accumulation.
// Q64 [bh][n][d] f64 ; K64 [bh][m][d] f64 ; Kt32 [bh][d][m] f32 ; V [bh][n][d] f32
// ---------------------------------------------------------------------------
__global__ __launch_bounds__(256) void qkv_gemm(const float* __restrict__ x,
                                                const float* __restrict__ w,
                                                double* __restrict__ Q,
                                                double* __restrict__ K64,
                                                float* __restrict__ Kt32,
                                                float* __restrict__ V) {
    __shared__ double As[16][64];
    __shared__ double Bs[16][64];
    const int tid = threadIdx.x;
    const int bm = blockIdx.y * 64;   // row block (M=4096)
    const int bn = blockIdx.x * 64;   // col block (N=2304)
    const int lm = tid >> 2;          // 0..63
    const int lk = (tid & 3) << 2;    // 0,4,8,12
    const int tx = tid & 15, ty = tid >> 4;

    double acc[4][4] = {};
    for (int k0 = 0; k0 < CDIM; k0 += 16) {
        float4 av = *reinterpret_cast<const float4*>(&x[(bm + lm) * CDIM + k0 + lk]);
        float4 bv = *reinterpret_cast<const float4*>(&w[(bn + lm) * CDIM + k0 + lk]);
        As[lk + 0][lm] = (double)av.x; As[lk + 1][lm] = (double)av.y;
        As[lk + 2][lm] = (double)av.z; As[lk + 3][lm] = (double)av.w;
        Bs[lk + 0][lm] = (double)bv.x; Bs[lk + 1][lm] = (double)bv.y;
        Bs[lk + 2][lm] = (double)bv.z; Bs[lk + 3][lm] = (double)bv.w;
        __syncthreads();
#pragma unroll
        for (int k = 0; k < 16; ++k) {
            double aa[4], bb[4];
#pragma unroll
            for (int i = 0; i < 4; ++i) { aa[i] = As[k][ty * 4 + i]; bb[i] = Bs[k][tx * 4 + i]; }
#pragma unroll
            for (int i = 0; i < 4; ++i)
#pragma unroll
                for (int j = 0; j < 4; ++j) acc[i][j] += aa[i] * bb[j];
        }
        __syncthreads();
    }
    const int t  = bn / CDIM;
    const int hh = (bn % CDIM) >> 6;
    const int b  = bm >> 11;
    const int bh = b * NH + hh;
#pragma unroll
    for (int i = 0; i < 4; ++i) {
        int r = bm + ty * 4 + i;
        int n = r & (NSEQ - 1);
        if (t == 0) {
#pragma unroll
            for (int j = 0; j < 4; ++j)
                Q[((size_t)bh * NSEQ + n) * HD + tx * 4 + j] = acc[i][j];
        } else if (t == 2) {
            float4 v4 = make_float4((float)acc[i][0], (float)acc[i][1],
                                    (float)acc[i][2], (float)acc[i][3]);
            *reinterpret_cast<float4*>(&V[((size_t)bh * NSEQ + n) * HD + tx * 4]) = v4;
        } else {
#pragma unroll
            for (int j = 0; j < 4; ++j) {
                int d = tx * 4 + j;
                K64[((size_t)bh * NSEQ + n) * HD + d] = acc[i][j];
                Kt32[((size_t)bh * HD + d) * NSEQ + n] = (float)acc[i][j];
            }
        }
    }
}

// ---------------------------------------------------------------------------
// Kernel 2: f32 bulk scores -> u16-key candidate select -> f64 rescore of
// candidates -> 128-wide bitonic sort -> exact f64 softmax/top-p -> sparse PV
// block = 512 threads (8 waves), 8 rows of one (b,h); wave w owns row w
// ---------------------------------------------------------------------------
__device__ inline unsigned long long d2key(double f) {
    unsigned long long u = (unsigned long long)__double_as_longlong(f);
    return u ^ (unsigned long long)(((long long)u >> 63) | (long long)0x8000000000000000ull);
}
__device__ inline double key2d(unsigned long long k) {
    unsigned long long mask = ((long long)k < 0) ? 0x8000000000000000ull : 0xFFFFFFFFFFFFFFFFull;
    return __longlong_as_double((long long)(k ^ mask));
}
// pack two f32 scores into two monotone u16 keys (truncated monotone u32 map)
__device__ inline unsigned kp(float a, float b) {
    unsigned ua = __float_as_uint(a);
    ua ^= (unsigned)(((int)ua >> 31) | 0x80000000);
    unsigned ub = __float_as_uint(b);
    ub ^= (unsigned)(((int)ub >> 31) | 0x80000000);
    return (ua >> 16) | (ub & 0xFFFF0000u);
}

__global__ __launch_bounds__(512, 6) void attn_kernel(const double* __restrict__ Q,
                                                      const double* __restrict__ K64,
                                                      const float* __restrict__ Kt32,
                                                      const float* __restrict__ V,
                                                      const float* __restrict__ temp,
                                                      const int* __restrict__ topk_p,
                                                      float* __restrict__ AO) {
    __shared__ unsigned short sk[8][NSEQ];   // 32 KB u16 keys
    __shared__ float qs32f[HD][8];           // [d][r] f32 scaled q
    __shared__ int cand[8][128];
    __shared__ int cnt8[8];

    const int tid  = threadIdx.x;              // 0..511
    const int bh   = blockIdx.x >> 8;          // 256 groups of 8 rows per (b,h)
    const int g0   = (blockIdx.x & 255) << 3;  // first row
    const int lane = tid & 63;
    const int wv   = tid >> 6;                 // 0..7

    const double scale = 0.125 * (double)temp[0];
    int TK = *topk_p;
    if (TK > 64) TK = 64;
    if (TK < 1)  TK = 1;

    if (tid < 8) cnt8[tid] = 0;
    // load q rows (scaled) as f32: thread (wv,lane) loads row wv, dim lane
    {
        double q = Q[((size_t)bh * NSEQ + g0 + wv) * HD + lane] * scale;
        qs32f[lane][wv] = (float)q;
    }
    __syncthreads();

    // ---- phase 2: f32 scores, thread owns 4 consecutive columns for all 8 rows
    const float* kb = Kt32 + (size_t)bh * HD * NSEQ;
    const int m0 = tid * 4;
    float acc[8][4] = {};
#pragma unroll 2
    for (int d = 0; d < HD; ++d) {
        const float* kr = kb + (size_t)d * NSEQ + m0;
        float4 k4 = *reinterpret_cast<const float4*>(kr);
        float kv[4] = {k4.x, k4.y, k4.z, k4.w};
        float4 qA = *reinterpret_cast<const float4*>(&qs32f[d][0]);
        float4 qB = *reinterpret_cast<const float4*>(&qs32f[d][4]);
        float qa[8] = {qA.x, qA.y, qA.z, qA.w, qB.x, qB.y, qB.z, qB.w};
#pragma unroll
        for (int r = 0; r < 8; ++r)
#pragma unroll
            for (int c = 0; c < 4; ++c) acc[r][c] = fmaf(qa[r], kv[c], acc[r][c]);
    }
#pragma unroll
    for (int r = 0; r < 8; ++r) {
        uint2 pkv;
        pkv.x = kp(acc[r][0], acc[r][1]);
        pkv.y = kp(acc[r][2], acc[r][3]);
        *reinterpret_cast<uint2*>(&sk[r][m0]) = pkv;
    }
    __syncthreads();

    // ---- phase 3: wave wv owns row wv
    const double* qbase = Q + (size_t)bh * NSEQ * HD;
    const double* kk64  = K64 + (size_t)bh * NSEQ * HD;
    const float*  vb    = V + (size_t)bh * NSEQ * HD;

    const int r = wv;
    const int row = g0 + r;

    int k32[32];
#pragma unroll
    for (int i = 0; i < 32; ++i) k32[i] = sk[r][i * 64 + lane];

    // early-stopped binary search on u16 keys: largest lo with count(>=lo) >= TK,
    // stop once that count <= 96
    int lo = 0, hi = 65535, clo = NSEQ;
    while (lo < hi && clo > 96) {
        int mid = (lo + hi + 1) >> 1;
        int c = 0;
#pragma unroll
        for (int i = 0; i < 32; ++i) c += (k32[i] >= mid) ? 1 : 0;
#pragma unroll
        for (int off = 32; off > 0; off >>= 1) c += __shfl_xor(c, off);
        if (c >= TK) { lo = mid; clo = c; } else hi = mid - 1;
    }
    int thr = lo >= 2 ? lo - 2 : 0;   // 2-ulp margin covers f32-dot + trunc error

    // compact candidate column indices
#pragma unroll
    for (int i = 0; i < 32; ++i) {
        if (k32[i] >= thr) {
            int slot = atomicAdd(&cnt8[r], 1);
            if (slot < 128) cand[r][slot] = i * 64 + lane;
        }
    }
    asm volatile("s_waitcnt lgkmcnt(0)" ::: "memory");
    int ncand = cnt8[r];
    if (ncand > 128) ncand = 128;

    // f64 rescore (bit-identical to reference chain: q*scale then d-seq fma)
    int c2 = 64 + lane;
    int m1 = cand[r][min(lane, ncand - 1)];
    int m2 = cand[r][min(c2, ncand - 1)];
    const double* qrow = qbase + (size_t)row * HD;
    const double* k1p = kk64 + (size_t)m1 * HD;
    const double* k2p = kk64 + (size_t)m2 * HD;
    double a1 = 0.0, a2 = 0.0;
#pragma unroll 4
    for (int d = 0; d < HD; ++d) {
        double qd = qrow[d] * scale;
        a1 = fma(qd, k1p[d], a1);
        a2 = fma(qd, k2p[d], a2);
    }
    unsigned long long kk1 = (lane < ncand) ? d2key(a1) : 0ull;
    unsigned long long kk2 = (c2 < ncand) ? d2key(a2) : 0ull;

    // bitonic sort of 128 (2/lane), ascending in t=~key == descending by key
    unsigned long long t0 = ~kk1, t1 = ~kk2;
    unsigned q0 = (unsigned)m1, q1 = (unsigned)m2;
#pragma unroll
    for (int k = 2; k <= 64; k <<= 1) {
#pragma unroll
        for (int j = k >> 1; j > 0; j >>= 1) {
            {
                unsigned long long ot = __shfl_xor(t0, j);
                unsigned om = __shfl_xor(q0, j);
                bool dir = (lane & k) != 0;
                bool lower = (lane & j) == 0;
                bool takeMin = (lower != dir);
                bool less = t0 < ot;
                bool self = (takeMin == less);
                t0 = self ? t0 : ot; q0 = self ? q0 : om;
            }
            {
                unsigned long long ot = __shfl_xor(t1, j);
                unsigned om = __shfl_xor(q1, j);
                bool dir = (k == 64) ? true : ((lane & k) != 0);
                bool lower = (lane & j) == 0;
                bool takeMin = (lower != dir);
                bool less = t1 < ot;
                bool self = (takeMin == less);
                t1 = self ? t1 : ot; q1 = self ? q1 : om;
            }
        }
    }
    {   // k=128, j=64: cross-slot local exchange (ascending: slot0 keeps min)
        bool sw = t1 < t0;
        unsigned long long na = sw ? t1 : t0, nb = sw ? t0 : t1;
        unsigned ma = sw ? q1 : q0, mb = sw ? q0 : q1;
        t0 = na; t1 = nb; q0 = ma; q1 = mb;
    }
#pragma unroll
    for (int j = 32; j > 0; j >>= 1) {
        {
            unsigned long long ot = __shfl_xor(t0, j);
            unsigned om = __shfl_xor(q0, j);
            bool lower = (lane & j) == 0;
            bool less = t0 < ot;
            bool self = (lower == less);
            t0 = self ? t0 : ot; q0 = self ? q0 : om;
        }
        {
            unsigned long long ot = __shfl_xor(t1, j);
            unsigned om = __shfl_xor(q1, j);
            bool lower = (lane & j) == 0;
            bool less = t1 < ot;
            bool self = (lower == less);
            t1 = self ? t1 : ot; q1 = self ? q1 : om;
        }
    }
    // lane l of slot0 = l-th largest by exact f64 key
    unsigned long long kk = ~t0;
    bool valid = lane < TK;
    double a = valid ? key2d(kk) : 0.0;
    double amax = __shfl(a, 0);
    double s = valid ? exp(a - amax) : 0.0;

    double ps = s;
#pragma unroll
    for (int off = 1; off < 64; off <<= 1) {
        double tt = __shfl_up(ps, off);
        if (lane >= off) ps += tt;
    }
    double S = __shfl(ps, 63);
    double cumprev = (ps - s) / S;
    bool keep = valid && ((lane == 0) || (cumprev <= 0.9));
    double sk2 = keep ? s : 0.0;
    double S2 = sk2;
#pragma unroll
    for (int off = 32; off > 0; off >>= 1) S2 += __shfl_xor(S2, off);
    float p = (float)(keep ? (s / S2) : 0.0);

    unsigned long long bal = __ballot(keep);
    int nk = __popcll(bal);

    float o = 0.f;
    for (int i = 0; i < nk; ++i) {
        float pi = __shfl(p, i);
        int midx = __shfl((int)q0, i);
        o += pi * vb[(size_t)midx * HD + lane];
    }
    const int b = bh / NH, hh = bh % NH;
    AO[((size_t)b * NSEQ + row) * CDIM + hh * HD + lane] = o;
}

// ---------------------------------------------------------------------------
// Kernel 3: out = AO @ proj_w^T + proj_b   (f32)
// ---------------------------------------------------------------------------
__global__ __launch_bounds__(256) void proj_gemm(const float* __restrict__ A,
                                                 const float* __restrict__ w,
                                                 const float* __restrict__ bias,
                                                 float* __restrict__ out) {
    __shared__ float As[16][64];
    __shared__ float Bs[16][64];
    const int tid = threadIdx.x;
    const int bm = blockIdx.y * 64;
    const int bn = blockIdx.x * 64;
    const int lm = tid >> 2;
    const int lk = (tid & 3) << 2;
    const int tx = tid & 15, ty = tid >> 4;

    float acc[4][4] = {};
    for (int k0 = 0; k0 < CDIM; k0 += 16) {
        float4 av = *reinterpret_cast<const float4*>(&A[(bm + lm) * CDIM + k0 + lk]);
        float4 bv = *reinterpret_cast<const float4*>(&w[(bn + lm) * CDIM + k0 + lk]);
        As[lk + 0][lm] = av.x; As[lk + 1][lm] = av.y; As[lk + 2][lm] = av.z; As[lk + 3][lm] = av.w;
        Bs[lk + 0][lm] = bv.x; Bs[lk + 1][lm] = bv.y; Bs[lk + 2][lm] = bv.z; Bs[lk + 3][lm] = bv.w;
        __syncthreads();
#pragma unroll
        for (int k = 0; k < 16; ++k) {
            float4 a4 = *reinterpret_cast<const float4*>(&As[k][ty * 4]);
            float4 b4 = *reinterpret_cast<const float4*>(&Bs[k][tx * 4]);
            float aa[4] = {a4.x, a4.y, a4.z, a4.w};
            float bb[4] = {b4.x, b4.y, b4.z, b4.w};
#pragma unroll
            for (int i = 0; i < 4; ++i)
#pragma unroll
                for (int j = 0; j < 4; ++j) acc[i][j] += aa[i] * bb[j];
        }
        __syncthreads();
    }
    float4 bv = *reinterpret_cast<const float4*>(&bias[bn + tx * 4]);
#pragma unroll
    for (int i = 0; i < 4; ++i) {
        int r = bm + ty * 4 + i;
        float4 v4 = make_float4(acc[i][0] + bv.x, acc[i][1] + bv.y,
                                acc[i][2] + bv.z, acc[i][3] + bv.w);
        *reinterpret_cast<float4*>(&out[(size_t)r * CDIM + bn + tx * 4]) = v4;
    }
}

// ---------------------------------------------------------------------------
extern "C" void kernel_launch(void* const* d_in, const int* in_sizes, int n_in,
                              void* d_out, int out_size, void* d_ws, size_t ws_size,
                              hipStream_t stream) {
    const float* x      = (const float*)d_in[0];
    const float* qkv_w  = (const float*)d_in[1];
    const float* proj_w = (const float*)d_in[2];
    const float* proj_b = (const float*)d_in[3];
    const float* temp   = (const float*)d_in[4];
    const int*   topk   = (const int*)d_in[5];
    float* out = (float*)d_out;

    const size_t HSZ = (size_t)NB * NH * NSEQ * HD;  // 3,145,728 elements
    double* Q64  = (double*)d_ws;          // 24 MB
    double* K64  = Q64 + HSZ;              // 24 MB
    float*  Kt32 = (float*)(K64 + HSZ);    // 12 MB
    float*  V    = Kt32 + HSZ;             // 12 MB
    float*  AO   = V + HSZ;                // 12 MB

    qkv_gemm<<<dim3(36, 64), 256, 0, stream>>>(x, qkv_w, Q64, K64, Kt32, V);
    attn_kernel<<<dim3(NB * NH * (NSEQ / 8)), 512, 0, stream>>>(Q64, K64, Kt32, V, temp, topk, AO);
    proj_gemm<<<dim3(12, 64), 256, 0, stream>>>(AO, proj_w, proj_b, out);
}

// Round 5
// 1023.091 us; speedup vs baseline: 1.8960x; 1.0652x over previous
//
#include <hip/hip_runtime.h>
#include <cstdint>

#define NH 12
#define HD 64
#define NSEQ 2048
#define CDIM 768
#define NB 2

// ---------------------------------------------------------------------------
// Kernel 1a: Q,K = x @ qkv_w[0:1536]^T with f64 accumulation.
// 128x64 tile, 8x4 per thread, f32 LDS staging (cvt to f64 at FMA).
// Outputs: Q64/K64 [bh][n][d] f64 (raw), Qs32 [bh][n][d] f32, Kt32 [bh][d][n] f32
// ---------------------------------------------------------------------------
__global__ __launch_bounds__(256, 4) void qkv_qk(const float* __restrict__ x,
                                                 const float* __restrict__ w,
                                                 double* __restrict__ Q64,
                                                 double* __restrict__ K64,
                                                 float* __restrict__ Qs32,
                                                 float* __restrict__ Kt32) {
    __shared__ float As[16][128];
    __shared__ float Bs[16][64];
    const int tid = threadIdx.x;
    const int bm = blockIdx.y * 128;      // M = 4096
    const int bn = blockIdx.x * 64;       // N = 1536 (Q,K only)
    const int alm = tid >> 1, alk = (tid & 1) * 8;
    const int blm = tid & 63, blk = (tid >> 6) * 4;
    const int tx = tid & 15, ty = tid >> 4;   // tx: 4 cols, ty: 8 rows

    double acc[8][4] = {};
    for (int k0 = 0; k0 < CDIM; k0 += 16) {
        float4 a0 = *reinterpret_cast<const float4*>(&x[(bm + alm) * CDIM + k0 + alk]);
        float4 a1 = *reinterpret_cast<const float4*>(&x[(bm + alm) * CDIM + k0 + alk + 4]);
        float4 b0 = *reinterpret_cast<const float4*>(&w[(bn + blm) * CDIM + k0 + blk]);
        __syncthreads();
        As[alk + 0][alm] = a0.x; As[alk + 1][alm] = a0.y;
        As[alk + 2][alm] = a0.z; As[alk + 3][alm] = a0.w;
        As[alk + 4][alm] = a1.x; As[alk + 5][alm] = a1.y;
        As[alk + 6][alm] = a1.z; As[alk + 7][alm] = a1.w;
        Bs[blk + 0][blm] = b0.x; Bs[blk + 1][blm] = b0.y;
        Bs[blk + 2][blm] = b0.z; Bs[blk + 3][blm] = b0.w;
        __syncthreads();
#pragma unroll
        for (int k = 0; k < 16; ++k) {
            float4 af0 = *reinterpret_cast<const float4*>(&As[k][ty * 8]);
            float4 af1 = *reinterpret_cast<const float4*>(&As[k][ty * 8 + 4]);
            float4 bf  = *reinterpret_cast<const float4*>(&Bs[k][tx * 4]);
            double ad[8] = {(double)af0.x, (double)af0.y, (double)af0.z, (double)af0.w,
                            (double)af1.x, (double)af1.y, (double)af1.z, (double)af1.w};
            double bd[4] = {(double)bf.x, (double)bf.y, (double)bf.z, (double)bf.w};
#pragma unroll
            for (int i = 0; i < 8; ++i)
#pragma unroll
                for (int j = 0; j < 4; ++j) acc[i][j] = fma(ad[i], bd[j], acc[i][j]);
        }
        __syncthreads();
    }
    const bool isQ = bn < CDIM;
    const int hh = (isQ ? bn : bn - CDIM) >> 6;
    const int b  = bm >> 11;
    const int bh = b * NH + hh;
#pragma unroll
    for (int i = 0; i < 8; ++i) {
        const int n = (bm + ty * 8 + i) & (NSEQ - 1);
        const size_t base = ((size_t)bh * NSEQ + n) * HD + tx * 4;
        if (isQ) {
            double2 d01; d01.x = acc[i][0]; d01.y = acc[i][1];
            double2 d23; d23.x = acc[i][2]; d23.y = acc[i][3];
            *reinterpret_cast<double2*>(&Q64[base]) = d01;
            *reinterpret_cast<double2*>(&Q64[base + 2]) = d23;
            *reinterpret_cast<float4*>(&Qs32[base]) =
                make_float4((float)acc[i][0], (float)acc[i][1], (float)acc[i][2], (float)acc[i][3]);
        } else {
            double2 d01; d01.x = acc[i][0]; d01.y = acc[i][1];
            double2 d23; d23.x = acc[i][2]; d23.y = acc[i][3];
            *reinterpret_cast<double2*>(&K64[base]) = d01;
            *reinterpret_cast<double2*>(&K64[base + 2]) = d23;
#pragma unroll
            for (int j = 0; j < 4; ++j)
                Kt32[((size_t)bh * HD + tx * 4 + j) * NSEQ + n] = (float)acc[i][j];
        }
    }
}

// ---------------------------------------------------------------------------
// Kernel 1b: V = x @ qkv_w[1536:2304]^T, f32 (64x64 tile, 4x4/thread)
// ---------------------------------------------------------------------------
__global__ __launch_bounds__(256) void qkv_v(const float* __restrict__ x,
                                             const float* __restrict__ wv,
                                             float* __restrict__ V) {
    __shared__ float As[16][64];
    __shared__ float Bs[16][64];
    const int tid = threadIdx.x;
    const int bm = blockIdx.y * 64;
    const int bn = blockIdx.x * 64;    // 0..767 relative to V block
    const int lm = tid >> 2;
    const int lk = (tid & 3) << 2;
    const int tx = tid & 15, ty = tid >> 4;

    float acc[4][4] = {};
    for (int k0 = 0; k0 < CDIM; k0 += 16) {
        float4 av = *reinterpret_cast<const float4*>(&x[(bm + lm) * CDIM + k0 + lk]);
        float4 bv = *reinterpret_cast<const float4*>(&wv[(bn + lm) * CDIM + k0 + lk]);
        __syncthreads();
        As[lk + 0][lm] = av.x; As[lk + 1][lm] = av.y; As[lk + 2][lm] = av.z; As[lk + 3][lm] = av.w;
        Bs[lk + 0][lm] = bv.x; Bs[lk + 1][lm] = bv.y; Bs[lk + 2][lm] = bv.z; Bs[lk + 3][lm] = bv.w;
        __syncthreads();
#pragma unroll
        for (int k = 0; k < 16; ++k) {
            float4 a4 = *reinterpret_cast<const float4*>(&As[k][ty * 4]);
            float4 b4 = *reinterpret_cast<const float4*>(&Bs[k][tx * 4]);
            float aa[4] = {a4.x, a4.y, a4.z, a4.w};
            float bb[4] = {b4.x, b4.y, b4.z, b4.w};
#pragma unroll
            for (int i = 0; i < 4; ++i)
#pragma unroll
                for (int j = 0; j < 4; ++j) acc[i][j] = fmaf(aa[i], bb[j], acc[i][j]);
        }
    }
    const int hh = bn >> 6;
    const int b  = bm >> 11;
#pragma unroll
    for (int i = 0; i < 4; ++i) {
        const int n = (bm + ty * 4 + i) & (NSEQ - 1);
        *reinterpret_cast<float4*>(&V[(((size_t)b * NH + hh) * NSEQ + n) * HD + tx * 4]) =
            make_float4(acc[i][0], acc[i][1], acc[i][2], acc[i][3]);
    }
}

// ---------------------------------------------------------------------------
// Kernel 2: f32 bulk scores -> u16-key candidates -> f64 rescore -> packed
// 128-wide bitonic -> exact f64 softmax/top-p -> sparse PV
// block = 512 threads (8 waves), 8 rows of one (b,h); wave w owns row w
// ---------------------------------------------------------------------------
__device__ inline unsigned long long d2key(double f) {
    unsigned long long u = (unsigned long long)__double_as_longlong(f);
    return u ^ (unsigned long long)(((long long)u >> 63) | (long long)0x8000000000000000ull);
}
__device__ inline double key2d(unsigned long long k) {
    unsigned long long mask = ((long long)k < 0) ? 0x8000000000000000ull : 0xFFFFFFFFFFFFFFFFull;
    return __longlong_as_double((long long)(k ^ mask));
}
__device__ inline unsigned kp(float a, float b) {
    unsigned ua = __float_as_uint(a);
    ua ^= (unsigned)(((int)ua >> 31) | 0x80000000);
    unsigned ub = __float_as_uint(b);
    ub ^= (unsigned)(((int)ub >> 31) | 0x80000000);
    return (ua >> 16) | (ub & 0xFFFF0000u);
}

__global__ __launch_bounds__(512, 6) void attn_kernel(const double* __restrict__ Q64,
                                                      const double* __restrict__ K64,
                                                      const float* __restrict__ Qs32,
                                                      const float* __restrict__ Kt32,
                                                      const float* __restrict__ V,
                                                      const float* __restrict__ temp,
                                                      const int* __restrict__ topk_p,
                                                      float* __restrict__ AO) {
    __shared__ unsigned short sk[8][NSEQ];   // 32 KB u16 proxy keys
    __shared__ int cand[8][128];
    __shared__ int cnt8[8];

    const int tid  = threadIdx.x;              // 0..511
    const int bh   = blockIdx.x >> 8;
    const int g0   = (blockIdx.x & 255) << 3;
    const int lane = tid & 63;
    const int wv   = tid >> 6;

    const double scale = 0.125 * (double)temp[0];
    const float sc32 = (float)scale;
    int TK = *topk_p;
    if (TK > 64) TK = 64;
    if (TK < 1)  TK = 1;

    if (tid < 8) cnt8[tid] = 0;
    __syncthreads();

    // ---- phase 2: raw f32 dots; thread owns 4 cols for all 8 rows.
    // q read via block-uniform scalar loads (SGPR), no LDS.
    const float* __restrict__ kb = Kt32 + (size_t)bh * HD * NSEQ;
    const float* __restrict__ qp = Qs32 + ((size_t)bh * NSEQ + g0) * HD;  // qp[r*64+d]
    const int m0 = tid * 4;
    float acc[8][4] = {};
#pragma unroll 4
    for (int d = 0; d < HD; ++d) {
        float4 k4 = *reinterpret_cast<const float4*>(&kb[(size_t)d * NSEQ + m0]);
        float kv[4] = {k4.x, k4.y, k4.z, k4.w};
#pragma unroll
        for (int r8 = 0; r8 < 8; ++r8) {
            float qv = qp[r8 * HD + d];
#pragma unroll
            for (int c = 0; c < 4; ++c) acc[r8][c] = fmaf(qv, kv[c], acc[r8][c]);
        }
    }
#pragma unroll
    for (int r8 = 0; r8 < 8; ++r8) {
        uint2 pkv;
        pkv.x = kp(acc[r8][0] * sc32, acc[r8][1] * sc32);
        pkv.y = kp(acc[r8][2] * sc32, acc[r8][3] * sc32);
        *reinterpret_cast<uint2*>(&sk[r8][m0]) = pkv;
    }
    __syncthreads();

    // ---- phase 3: wave wv owns row wv
    const int r = wv;
    const int row = g0 + r;

    int k32[32];
#pragma unroll
    for (int i = 0; i < 32; ++i) k32[i] = sk[r][i * 64 + lane];

    // wave max of keys
    int mx = k32[0];
#pragma unroll
    for (int i = 1; i < 32; ++i) mx = max(mx, k32[i]);
#pragma unroll
    for (int off = 32; off > 0; off >>= 1) mx = max(mx, __shfl_xor(mx, off));

    // windowed binary search: largest lo with count(>=lo) >= TK, stop at count<=96
    int lo0 = mx > 1024 ? mx - 1024 : 0;
    int c0 = 0;
#pragma unroll
    for (int i = 0; i < 32; ++i) c0 += (k32[i] >= lo0) ? 1 : 0;
#pragma unroll
    for (int off = 32; off > 0; off >>= 1) c0 += __shfl_xor(c0, off);
    int lo, hi, clo;
    if (c0 >= TK) { lo = lo0; clo = c0; hi = mx; }
    else          { lo = 0;   clo = NSEQ; hi = lo0 - 1; }
    while (lo < hi && clo > 96) {
        int mid = lo + ((hi - lo + 1) >> 1);
        int c = 0;
#pragma unroll
        for (int i = 0; i < 32; ++i) c += (k32[i] >= mid) ? 1 : 0;
#pragma unroll
        for (int off = 32; off > 0; off >>= 1) c += __shfl_xor(c, off);
        if (c >= TK) { lo = mid; clo = c; } else hi = mid - 1;
    }
    int thr = lo >= 2 ? lo - 2 : 0;   // margin covers f32-dot + trunc error

    // compact candidate column indices
#pragma unroll
    for (int i = 0; i < 32; ++i) {
        if (k32[i] >= thr) {
            int slot = atomicAdd(&cnt8[r], 1);
            if (slot < 128) cand[r][slot] = i * 64 + lane;
        }
    }
    asm volatile("s_waitcnt lgkmcnt(0)" ::: "memory");
    int ncand = cnt8[r];
    if (ncand > 128) ncand = 128;

    // f64 rescore: a = (sum_d q_d * k_d) * scale  (q via uniform scalar loads)
    const int c2 = 64 + lane;
    const int m1 = cand[r][min(lane, ncand - 1)];
    const int m2 = cand[r][min(c2, ncand - 1)];
    const double* __restrict__ qrow = Q64 + ((size_t)bh * NSEQ + row) * HD;
    const double* __restrict__ k1p = K64 + ((size_t)bh * NSEQ + m1) * HD;
    const double* __restrict__ k2p = K64 + ((size_t)bh * NSEQ + m2) * HD;
    double a1 = 0.0, a2 = 0.0;
#pragma unroll 4
    for (int d = 0; d < HD; ++d) {
        double qd = qrow[d];
        a1 = fma(qd, k1p[d], a1);
        a2 = fma(qd, k2p[d], a2);
    }
    a1 *= scale; a2 *= scale;

    // packed sort key: value bits [63:11] | (2047 - idx); 0 for invalid slots
    unsigned long long pk1 = (lane < ncand) ? ((d2key(a1) & ~2047ull) | (unsigned)(2047 - m1)) : 0ull;
    unsigned long long pk2 = (c2 < ncand)   ? ((d2key(a2) & ~2047ull) | (unsigned)(2047 - m2)) : 0ull;

    // 128-wide bitonic (2/lane), ascending in t = ~pk  == descending by pk
    unsigned long long t0 = ~pk1, t1 = ~pk2;
#pragma unroll
    for (int k = 2; k <= 64; k <<= 1) {
#pragma unroll
        for (int j = k >> 1; j > 0; j >>= 1) {
            {
                unsigned long long ot = __shfl_xor(t0, j);
                bool dir = (lane & k) != 0;
                bool lower = (lane & j) == 0;
                bool takeMin = (lower != dir);
                bool less = t0 < ot;
                t0 = (takeMin == less) ? t0 : ot;
            }
            {
                unsigned long long ot = __shfl_xor(t1, j);
                bool dir = (k == 64) ? true : ((lane & k) != 0);
                bool lower = (lane & j) == 0;
                bool takeMin = (lower != dir);
                bool less = t1 < ot;
                t1 = (takeMin == less) ? t1 : ot;
            }
        }
    }
    {   // k=128, j=64 cross-slot exchange
        unsigned long long na = (t1 < t0) ? t1 : t0;
        unsigned long long nb = (t1 < t0) ? t0 : t1;
        t0 = na; t1 = nb;
    }
#pragma unroll
    for (int j = 32; j > 0; j >>= 1) {
        {
            unsigned long long ot = __shfl_xor(t0, j);
            bool lower = (lane & j) == 0;
            bool less = t0 < ot;
            t0 = (lower == less) ? t0 : ot;
        }
        {
            unsigned long long ot = __shfl_xor(t1, j);
            bool lower = (lane & j) == 0;
            bool less = t1 < ot;
            t1 = (lower == less) ? t1 : ot;
        }
    }
    // lane l holds l-th largest candidate
    unsigned long long kk = ~t0;
    int mi = 2047 - (int)(kk & 2047ull);
    bool valid = lane < TK;
    double a = valid ? key2d(kk & ~2047ull) : 0.0;
    double amax = __shfl(a, 0);
    double s = valid ? exp(a - amax) : 0.0;

    double ps = s;
#pragma unroll
    for (int off = 1; off < 64; off <<= 1) {
        double tt = __shfl_up(ps, off);
        if (lane >= off) ps += tt;
    }
    double S = __shfl(ps, 63);
    double cumprev = (ps - s) / S;
    bool keep = valid && ((lane == 0) || (cumprev <= 0.9));
    double sk2 = keep ? s : 0.0;
    double S2 = sk2;
#pragma unroll
    for (int off = 32; off > 0; off >>= 1) S2 += __shfl_xor(S2, off);
    float p = (float)(keep ? (s / S2) : 0.0);

    unsigned long long bal = __ballot(keep);
    int nk = __popcll(bal);

    const float* __restrict__ vb = V + (size_t)bh * NSEQ * HD;
    float o = 0.f;
    for (int i = 0; i < nk; ++i) {
        float pi = __shfl(p, i);
        int midx = __shfl(mi, i);
        o = fmaf(pi, vb[(size_t)midx * HD + lane], o);
    }
    const int b = bh / NH, hh = bh % NH;
    AO[((size_t)b * NSEQ + row) * CDIM + hh * HD + lane] = o;
}

// ---------------------------------------------------------------------------
// Kernel 3: out = AO @ proj_w^T + proj_b   (f32)
// ---------------------------------------------------------------------------
__global__ __launch_bounds__(256) void proj_gemm(const float* __restrict__ A,
                                                 const float* __restrict__ w,
                                                 const float* __restrict__ bias,
                                                 float* __restrict__ out) {
    __shared__ float As[16][64];
    __shared__ float Bs[16][64];
    const int tid = threadIdx.x;
    const int bm = blockIdx.y * 64;
    const int bn = blockIdx.x * 64;
    const int lm = tid >> 2;
    const int lk = (tid & 3) << 2;
    const int tx = tid & 15, ty = tid >> 4;

    float acc[4][4] = {};
    for (int k0 = 0; k0 < CDIM; k0 += 16) {
        float4 av = *reinterpret_cast<const float4*>(&A[(bm + lm) * CDIM + k0 + lk]);
        float4 bv = *reinterpret_cast<const float4*>(&w[(bn + lm) * CDIM + k0 + lk]);
        __syncthreads();
        As[lk + 0][lm] = av.x; As[lk + 1][lm] = av.y; As[lk + 2][lm] = av.z; As[lk + 3][lm] = av.w;
        Bs[lk + 0][lm] = bv.x; Bs[lk + 1][lm] = bv.y; Bs[lk + 2][lm] = bv.z; Bs[lk + 3][lm] = bv.w;
        __syncthreads();
#pragma unroll
        for (int k = 0; k < 16; ++k) {
            float4 a4 = *reinterpret_cast<const float4*>(&As[k][ty * 4]);
            float4 b4 = *reinterpret_cast<const float4*>(&Bs[k][tx * 4]);
            float aa[4] = {a4.x, a4.y, a4.z, a4.w};
            float bb[4] = {b4.x, b4.y, b4.z, b4.w};
#pragma unroll
            for (int i = 0; i < 4; ++i)
#pragma unroll
                for (int j = 0; j < 4; ++j) acc[i][j] = fmaf(aa[i], bb[j], acc[i][j]);
        }
    }
    float4 bv = *reinterpret_cast<const float4*>(&bias[bn + tx * 4]);
#pragma unroll
    for (int i = 0; i < 4; ++i) {
        int r = bm + ty * 4 + i;
        float4 v4 = make_float4(acc[i][0] + bv.x, acc[i][1] + bv.y,
                                acc[i][2] + bv.z, acc[i][3] + bv.w);
        *reinterpret_cast<float4*>(&out[(size_t)r * CDIM + bn + tx * 4]) = v4;
    }
}

// ---------------------------------------------------------------------------
extern "C" void kernel_launch(void* const* d_in, const int* in_sizes, int n_in,
                              void* d_out, int out_size, void* d_ws, size_t ws_size,
                              hipStream_t stream) {
    const float* x      = (const float*)d_in[0];
    const float* qkv_w  = (const float*)d_in[1];
    const float* proj_w = (const float*)d_in[2];
    const float* proj_b = (const float*)d_in[3];
    const float* temp   = (const float*)d_in[4];
    const int*   topk   = (const int*)d_in[5];
    float* out = (float*)d_out;

    const size_t HSZ = (size_t)NB * NH * NSEQ * HD;  // 3,145,728 elements
    double* Q64  = (double*)d_ws;           // 24 MB
    double* K64  = Q64 + HSZ;               // 24 MB
    float*  Qs32 = (float*)(K64 + HSZ);     // 12 MB
    float*  Kt32 = Qs32 + HSZ;              // 12 MB
    float*  V    = Kt32 + HSZ;              // 12 MB
    float*  AO   = V + HSZ;                 // 12 MB  -> 96 MB total

    qkv_qk<<<dim3(24, 32), 256, 0, stream>>>(x, qkv_w, Q64, K64, Qs32, Kt32);
    qkv_v<<<dim3(12, 64), 256, 0, stream>>>(x, qkv_w + (size_t)2 * CDIM * CDIM, V);
    attn_kernel<<<dim3(NB * NH * (NSEQ / 8)), 512, 0, stream>>>(Q64, K64, Qs32, Kt32, V, temp, topk, AO);
    proj_gemm<<<dim3(12, 64), 256, 0, stream>>>(AO, proj_w, proj_b, out);
}

// Round 6
// 816.037 us; speedup vs baseline: 2.3770x; 1.2537x over previous
//
#include <hip/hip_runtime.h>
#include <cstdint>

#define NH 12
#define HD 64
#define NSEQ 2048
#define CDIM 768
#define NB 2

// ---------------------------------------------------------------------------
// Kernel 1a: Q,K = x @ qkv_w[0:1536]^T with f64 accumulation.
// 128x64 tile, 8x4 per thread, f32 LDS staging (cvt to f64 at FMA).
// Outputs: Q64/K64 [bh][n][d] f64 (raw), Qs32 [bh][n][d] f32, Kt32 [bh][d][n] f32
// ---------------------------------------------------------------------------
__global__ __launch_bounds__(256, 4) void qkv_qk(const float* __restrict__ x,
                                                 const float* __restrict__ w,
                                                 double* __restrict__ Q64,
                                                 double* __restrict__ K64,
                                                 float* __restrict__ Qs32,
                                                 float* __restrict__ Kt32) {
    __shared__ float As[16][128];
    __shared__ float Bs[16][64];
    const int tid = threadIdx.x;
    const int bm = blockIdx.y * 128;      // M = 4096
    const int bn = blockIdx.x * 64;       // N = 1536 (Q,K only)
    const int alm = tid >> 1, alk = (tid & 1) * 8;
    const int blm = tid & 63, blk = (tid >> 6) * 4;
    const int tx = tid & 15, ty = tid >> 4;   // tx: 4 cols, ty: 8 rows

    double acc[8][4] = {};
    for (int k0 = 0; k0 < CDIM; k0 += 16) {
        float4 a0 = *reinterpret_cast<const float4*>(&x[(bm + alm) * CDIM + k0 + alk]);
        float4 a1 = *reinterpret_cast<const float4*>(&x[(bm + alm) * CDIM + k0 + alk + 4]);
        float4 b0 = *reinterpret_cast<const float4*>(&w[(bn + blm) * CDIM + k0 + blk]);
        __syncthreads();
        As[alk + 0][alm] = a0.x; As[alk + 1][alm] = a0.y;
        As[alk + 2][alm] = a0.z; As[alk + 3][alm] = a0.w;
        As[alk + 4][alm] = a1.x; As[alk + 5][alm] = a1.y;
        As[alk + 6][alm] = a1.z; As[alk + 7][alm] = a1.w;
        Bs[blk + 0][blm] = b0.x; Bs[blk + 1][blm] = b0.y;
        Bs[blk + 2][blm] = b0.z; Bs[blk + 3][blm] = b0.w;
        __syncthreads();
#pragma unroll
        for (int k = 0; k < 16; ++k) {
            float4 af0 = *reinterpret_cast<const float4*>(&As[k][ty * 8]);
            float4 af1 = *reinterpret_cast<const float4*>(&As[k][ty * 8 + 4]);
            float4 bf  = *reinterpret_cast<const float4*>(&Bs[k][tx * 4]);
            double ad[8] = {(double)af0.x, (double)af0.y, (double)af0.z, (double)af0.w,
                            (double)af1.x, (double)af1.y, (double)af1.z, (double)af1.w};
            double bd[4] = {(double)bf.x, (double)bf.y, (double)bf.z, (double)bf.w};
#pragma unroll
            for (int i = 0; i < 8; ++i)
#pragma unroll
                for (int j = 0; j < 4; ++j) acc[i][j] = fma(ad[i], bd[j], acc[i][j]);
        }
        __syncthreads();
    }
    const bool isQ = bn < CDIM;
    const int hh = (isQ ? bn : bn - CDIM) >> 6;
    const int b  = bm >> 11;
    const int bh = b * NH + hh;
#pragma unroll
    for (int i = 0; i < 8; ++i) {
        const int n = (bm + ty * 8 + i) & (NSEQ - 1);
        const size_t base = ((size_t)bh * NSEQ + n) * HD + tx * 4;
        if (isQ) {
            double2 d01; d01.x = acc[i][0]; d01.y = acc[i][1];
            double2 d23; d23.x = acc[i][2]; d23.y = acc[i][3];
            *reinterpret_cast<double2*>(&Q64[base]) = d01;
            *reinterpret_cast<double2*>(&Q64[base + 2]) = d23;
            *reinterpret_cast<float4*>(&Qs32[base]) =
                make_float4((float)acc[i][0], (float)acc[i][1], (float)acc[i][2], (float)acc[i][3]);
        } else {
            double2 d01; d01.x = acc[i][0]; d01.y = acc[i][1];
            double2 d23; d23.x = acc[i][2]; d23.y = acc[i][3];
            *reinterpret_cast<double2*>(&K64[base]) = d01;
            *reinterpret_cast<double2*>(&K64[base + 2]) = d23;
#pragma unroll
            for (int j = 0; j < 4; ++j)
                Kt32[((size_t)bh * HD + tx * 4 + j) * NSEQ + n] = (float)acc[i][j];
        }
    }
}

// ---------------------------------------------------------------------------
// Kernel 1b: V = x @ qkv_w[1536:2304]^T, f32 (64x64 tile, 4x4/thread)
// ---------------------------------------------------------------------------
__global__ __launch_bounds__(256) void qkv_v(const float* __restrict__ x,
                                             const float* __restrict__ wv,
                                             float* __restrict__ V) {
    __shared__ float As[16][64];
    __shared__ float Bs[16][64];
    const int tid = threadIdx.x;
    const int bm = blockIdx.y * 64;
    const int bn = blockIdx.x * 64;    // 0..767 relative to V block
    const int lm = tid >> 2;
    const int lk = (tid & 3) << 2;
    const int tx = tid & 15, ty = tid >> 4;

    float acc[4][4] = {};
    for (int k0 = 0; k0 < CDIM; k0 += 16) {
        float4 av = *reinterpret_cast<const float4*>(&x[(bm + lm) * CDIM + k0 + lk]);
        float4 bv = *reinterpret_cast<const float4*>(&wv[(bn + lm) * CDIM + k0 + lk]);
        __syncthreads();
        As[lk + 0][lm] = av.x; As[lk + 1][lm] = av.y; As[lk + 2][lm] = av.z; As[lk + 3][lm] = av.w;
        Bs[lk + 0][lm] = bv.x; Bs[lk + 1][lm] = bv.y; Bs[lk + 2][lm] = bv.z; Bs[lk + 3][lm] = bv.w;
        __syncthreads();
#pragma unroll
        for (int k = 0; k < 16; ++k) {
            float4 a4 = *reinterpret_cast<const float4*>(&As[k][ty * 4]);
            float4 b4 = *reinterpret_cast<const float4*>(&Bs[k][tx * 4]);
            float aa[4] = {a4.x, a4.y, a4.z, a4.w};
            float bb[4] = {b4.x, b4.y, b4.z, b4.w};
#pragma unroll
            for (int i = 0; i < 4; ++i)
#pragma unroll
                for (int j = 0; j < 4; ++j) acc[i][j] = fmaf(aa[i], bb[j], acc[i][j]);
        }
    }
    const int hh = bn >> 6;
    const int b  = bm >> 11;
#pragma unroll
    for (int i = 0; i < 4; ++i) {
        const int n = (bm + ty * 4 + i) & (NSEQ - 1);
        *reinterpret_cast<float4*>(&V[(((size_t)b * NH + hh) * NSEQ + n) * HD + tx * 4]) =
            make_float4(acc[i][0], acc[i][1], acc[i][2], acc[i][3]);
    }
}

// ---------------------------------------------------------------------------
// Kernel 2: f32 bulk scores -> u16-key candidates -> group-coalesced f64
// rescore -> packed 128-wide bitonic -> exact f64 softmax/top-p -> sparse PV
// block = 512 threads (8 waves), 8 rows of one (b,h); wave w owns row w
// ---------------------------------------------------------------------------
__device__ inline unsigned long long d2key(double f) {
    unsigned long long u = (unsigned long long)__double_as_longlong(f);
    return u ^ (unsigned long long)(((long long)u >> 63) | (long long)0x8000000000000000ull);
}
__device__ inline double key2d(unsigned long long k) {
    unsigned long long mask = ((long long)k < 0) ? 0x8000000000000000ull : 0xFFFFFFFFFFFFFFFFull;
    return __longlong_as_double((long long)(k ^ mask));
}
__device__ inline unsigned kp(float a, float b) {
    unsigned ua = __float_as_uint(a);
    ua ^= (unsigned)(((int)ua >> 31) | 0x80000000);
    unsigned ub = __float_as_uint(b);
    ub ^= (unsigned)(((int)ub >> 31) | 0x80000000);
    return (ua >> 16) | (ub & 0xFFFF0000u);
}

__global__ __launch_bounds__(512, 6) void attn_kernel(const double* __restrict__ Q64,
                                                      const double* __restrict__ K64,
                                                      const float* __restrict__ Qs32,
                                                      const float* __restrict__ Kt32,
                                                      const float* __restrict__ V,
                                                      const float* __restrict__ temp,
                                                      const int* __restrict__ topk_p,
                                                      float* __restrict__ AO) {
    __shared__ unsigned short sk[8][NSEQ];   // 32 KB u16 proxy keys (row r's 4KB
                                             // later reused as 1KB packed-key scratch)
    __shared__ int cand[8][128];
    __shared__ int cnt8[8];

    const int tid  = threadIdx.x;              // 0..511
    const int bh   = blockIdx.x >> 8;
    const int g0   = (blockIdx.x & 255) << 3;
    const int lane = tid & 63;
    const int wv   = tid >> 6;

    const double scale = 0.125 * (double)temp[0];
    const float sc32 = (float)scale;
    int TK = *topk_p;
    if (TK > 64) TK = 64;
    if (TK < 1)  TK = 1;

    if (tid < 8) cnt8[tid] = 0;
    __syncthreads();

    // ---- phase 2: raw f32 dots; thread owns 4 cols for all 8 rows.
    // q read via block-uniform scalar loads (SGPR), no LDS.
    const float* __restrict__ kb = Kt32 + (size_t)bh * HD * NSEQ;
    const float* __restrict__ qp = Qs32 + ((size_t)bh * NSEQ + g0) * HD;  // qp[r*64+d]
    const int m0 = tid * 4;
    float acc[8][4] = {};
#pragma unroll 4
    for (int d = 0; d < HD; ++d) {
        float4 k4 = *reinterpret_cast<const float4*>(&kb[(size_t)d * NSEQ + m0]);
        float kv[4] = {k4.x, k4.y, k4.z, k4.w};
#pragma unroll
        for (int r8 = 0; r8 < 8; ++r8) {
            float qv = qp[r8 * HD + d];
#pragma unroll
            for (int c = 0; c < 4; ++c) acc[r8][c] = fmaf(qv, kv[c], acc[r8][c]);
        }
    }
#pragma unroll
    for (int r8 = 0; r8 < 8; ++r8) {
        uint2 pkv;
        pkv.x = kp(acc[r8][0] * sc32, acc[r8][1] * sc32);
        pkv.y = kp(acc[r8][2] * sc32, acc[r8][3] * sc32);
        *reinterpret_cast<uint2*>(&sk[r8][m0]) = pkv;
    }
    __syncthreads();

    // ---- phase 3: wave wv owns row wv
    const int r = wv;
    const int row = g0 + r;

    int k32[32];
#pragma unroll
    for (int i = 0; i < 32; ++i) k32[i] = sk[r][i * 64 + lane];

    // wave max of keys
    int mx = k32[0];
#pragma unroll
    for (int i = 1; i < 32; ++i) mx = max(mx, k32[i]);
#pragma unroll
    for (int off = 32; off > 0; off >>= 1) mx = max(mx, __shfl_xor(mx, off));

    // windowed binary search: largest lo with count(>=lo) >= TK, stop at count<=96
    int lo0 = mx > 1024 ? mx - 1024 : 0;
    int c0 = 0;
#pragma unroll
    for (int i = 0; i < 32; ++i) c0 += (k32[i] >= lo0) ? 1 : 0;
#pragma unroll
    for (int off = 32; off > 0; off >>= 1) c0 += __shfl_xor(c0, off);
    int lo, hi, clo;
    if (c0 >= TK) { lo = lo0; clo = c0; hi = mx; }
    else          { lo = 0;   clo = NSEQ; hi = lo0 - 1; }
    while (lo < hi && clo > 96) {
        int mid = lo + ((hi - lo + 1) >> 1);
        int c = 0;
#pragma unroll
        for (int i = 0; i < 32; ++i) c += (k32[i] >= mid) ? 1 : 0;
#pragma unroll
        for (int off = 32; off > 0; off >>= 1) c += __shfl_xor(c, off);
        if (c >= TK) { lo = mid; clo = c; } else hi = mid - 1;
    }
    int thr = lo >= 2 ? lo - 2 : 0;   // margin covers f32-dot + trunc error

    // compact candidate column indices
#pragma unroll
    for (int i = 0; i < 32; ++i) {
        if (k32[i] >= thr) {
            int slot = atomicAdd(&cnt8[r], 1);
            if (slot < 128) cand[r][slot] = i * 64 + lane;
        }
    }
    asm volatile("s_waitcnt lgkmcnt(0)" ::: "memory");
    int ncand = cnt8[r];
    if (ncand > 128) ncand = 128;

    // ---- group-coalesced f64 rescore: 8 groups x 8 lanes; group g owns slots
    // 16g..16g+15; lane sl reads k[m][sl*8..sl*8+8) (contiguous 512B per group)
    const int gidx = lane >> 3;
    const int sl   = lane & 7;
    const double* __restrict__ qrow = Q64 + ((size_t)bh * NSEQ + row) * HD;
    double qd[8];
#pragma unroll
    for (int j = 0; j < 8; ++j) qd[j] = qrow[sl * 8 + j];

    unsigned long long* pkr = reinterpret_cast<unsigned long long*>(&sk[r][0]);
    const double* __restrict__ kbase = K64 + (size_t)bh * NSEQ * HD;
#pragma unroll 2
    for (int j = 0; j < 16; ++j) {
        const int s = gidx * 16 + j;
        const int ms = cand[r][min(s, ncand - 1)];
        const double* __restrict__ kp8 = kbase + (size_t)ms * HD + sl * 8;
        double a = 0.0;
#pragma unroll
        for (int d = 0; d < 8; ++d) a = fma(qd[d], kp8[d], a);
        // 8-lane tree reduction (deterministic f64 order)
        a += __shfl_xor(a, 1);
        a += __shfl_xor(a, 2);
        a += __shfl_xor(a, 4);
        a *= scale;
        unsigned long long pkv = (s < ncand)
            ? ((d2key(a) & ~2047ull) | (unsigned long long)(2047 - ms)) : 0ull;
        if (sl == (j & 7)) pkr[s] = pkv;
    }
    asm volatile("s_waitcnt lgkmcnt(0)" ::: "memory");
    unsigned long long pk1 = pkr[lane];
    unsigned long long pk2 = pkr[64 + lane];

    // 128-wide bitonic (2/lane), ascending in t = ~pk  == descending by pk
    unsigned long long t0 = ~pk1, t1 = ~pk2;
#pragma unroll
    for (int k = 2; k <= 64; k <<= 1) {
#pragma unroll
        for (int j = k >> 1; j > 0; j >>= 1) {
            {
                unsigned long long ot = __shfl_xor(t0, j);
                bool dir = (lane & k) != 0;
                bool lower = (lane & j) == 0;
                bool takeMin = (lower != dir);
                bool less = t0 < ot;
                t0 = (takeMin == less) ? t0 : ot;
            }
            {
                unsigned long long ot = __shfl_xor(t1, j);
                bool dir = (k == 64) ? true : ((lane & k) != 0);
                bool lower = (lane & j) == 0;
                bool takeMin = (lower != dir);
                bool less = t1 < ot;
                t1 = (takeMin == less) ? t1 : ot;
            }
        }
    }
    {   // k=128, j=64 cross-slot exchange
        unsigned long long na = (t1 < t0) ? t1 : t0;
        unsigned long long nb = (t1 < t0) ? t0 : t1;
        t0 = na; t1 = nb;
    }
#pragma unroll
    for (int j = 32; j > 0; j >>= 1) {
        {
            unsigned long long ot = __shfl_xor(t0, j);
            bool lower = (lane & j) == 0;
            bool less = t0 < ot;
            t0 = (lower == less) ? t0 : ot;
        }
        {
            unsigned long long ot = __shfl_xor(t1, j);
            bool lower = (lane & j) == 0;
            bool less = t1 < ot;
            t1 = (lower == less) ? t1 : ot;
        }
    }
    // lane l holds l-th largest candidate
    unsigned long long kk = ~t0;
    int mi = 2047 - (int)(kk & 2047ull);
    bool valid = lane < TK;
    double a = valid ? key2d(kk & ~2047ull) : 0.0;
    double amax = __shfl(a, 0);
    double s = valid ? exp(a - amax) : 0.0;

    double ps = s;
#pragma unroll
    for (int off = 1; off < 64; off <<= 1) {
        double tt = __shfl_up(ps, off);
        if (lane >= off) ps += tt;
    }
    double S = __shfl(ps, 63);
    double cumprev = (ps - s) / S;
    bool keep = valid && ((lane == 0) || (cumprev <= 0.9));
    double sk2 = keep ? s : 0.0;
    double S2 = sk2;
#pragma unroll
    for (int off = 32; off > 0; off >>= 1) S2 += __shfl_xor(S2, off);
    float p = (float)(keep ? (s / S2) : 0.0);

    unsigned long long bal = __ballot(keep);
    int nk = __popcll(bal);

    const float* __restrict__ vb = V + (size_t)bh * NSEQ * HD;
    float o = 0.f;
    for (int i = 0; i < nk; ++i) {
        float pi = __shfl(p, i);
        int midx = __shfl(mi, i);
        o = fmaf(pi, vb[(size_t)midx * HD + lane], o);
    }
    const int b = bh / NH, hh = bh % NH;
    AO[((size_t)b * NSEQ + row) * CDIM + hh * HD + lane] = o;
}

// ---------------------------------------------------------------------------
// Kernel 3: out = AO @ proj_w^T + proj_b   (f32)
// ---------------------------------------------------------------------------
__global__ __launch_bounds__(256) void proj_gemm(const float* __restrict__ A,
                                                 const float* __restrict__ w,
                                                 const float* __restrict__ bias,
                                                 float* __restrict__ out) {
    __shared__ float As[16][64];
    __shared__ float Bs[16][64];
    const int tid = threadIdx.x;
    const int bm = blockIdx.y * 64;
    const int bn = blockIdx.x * 64;
    const int lm = tid >> 2;
    const int lk = (tid & 3) << 2;
    const int tx = tid & 15, ty = tid >> 4;

    float acc[4][4] = {};
    for (int k0 = 0; k0 < CDIM; k0 += 16) {
        float4 av = *reinterpret_cast<const float4*>(&A[(bm + lm) * CDIM + k0 + lk]);
        float4 bv = *reinterpret_cast<const float4*>(&w[(bn + lm) * CDIM + k0 + lk]);
        __syncthreads();
        As[lk + 0][lm] = av.x; As[lk + 1][lm] = av.y; As[lk + 2][lm] = av.z; As[lk + 3][lm] = av.w;
        Bs[lk + 0][lm] = bv.x; Bs[lk + 1][lm] = bv.y; Bs[lk + 2][lm] = bv.z; Bs[lk + 3][lm] = bv.w;
        __syncthreads();
#pragma unroll
        for (int k = 0; k < 16; ++k) {
            float4 a4 = *reinterpret_cast<const float4*>(&As[k][ty * 4]);
            float4 b4 = *reinterpret_cast<const float4*>(&Bs[k][tx * 4]);
            float aa[4] = {a4.x, a4.y, a4.z, a4.w};
            float bb[4] = {b4.x, b4.y, b4.z, b4.w};
#pragma unroll
            for (int i = 0; i < 4; ++i)
#pragma unroll
                for (int j = 0; j < 4; ++j) acc[i][j] = fmaf(aa[i], bb[j], acc[i][j]);
        }
    }
    float4 bv = *reinterpret_cast<const float4*>(&bias[bn + tx * 4]);
#pragma unroll
    for (int i = 0; i < 4; ++i) {
        int r = bm + ty * 4 + i;
        float4 v4 = make_float4(acc[i][0] + bv.x, acc[i][1] + bv.y,
                                acc[i][2] + bv.z, acc[i][3] + bv.w);
        *reinterpret_cast<float4*>(&out[(size_t)r * CDIM + bn + tx * 4]) = v4;
    }
}

// ---------------------------------------------------------------------------
extern "C" void kernel_launch(void* const* d_in, const int* in_sizes, int n_in,
                              void* d_out, int out_size, void* d_ws, size_t ws_size,
                              hipStream_t stream) {
    const float* x      = (const float*)d_in[0];
    const float* qkv_w  = (const float*)d_in[1];
    const float* proj_w = (const float*)d_in[2];
    const float* proj_b = (const float*)d_in[3];
    const float* temp   = (const float*)d_in[4];
    const int*   topk   = (const int*)d_in[5];
    float* out = (float*)d_out;

    const size_t HSZ = (size_t)NB * NH * NSEQ * HD;  // 3,145,728 elements
    double* Q64  = (double*)d_ws;           // 24 MB
    double* K64  = Q64 + HSZ;               // 24 MB
    float*  Qs32 = (float*)(K64 + HSZ);     // 12 MB
    float*  Kt32 = Qs32 + HSZ;              // 12 MB
    float*  V    = Kt32 + HSZ;              // 12 MB
    float*  AO   = V + HSZ;                 // 12 MB  -> 96 MB total

    qkv_qk<<<dim3(24, 32), 256, 0, stream>>>(x, qkv_w, Q64, K64, Qs32, Kt32);
    qkv_v<<<dim3(12, 64), 256, 0, stream>>>(x, qkv_w + (size_t)2 * CDIM * CDIM, V);
    attn_kernel<<<dim3(NB * NH * (NSEQ / 8)), 512, 0, stream>>>(Q64, K64, Qs32, Kt32, V, temp, topk, AO);
    proj_gemm<<<dim3(12, 64), 256, 0, stream>>>(AO, proj_w, proj_b, out);
}

// Round 7
// 790.865 us; speedup vs baseline: 2.4527x; 1.0318x over previous
//
#include <hip/hip_runtime.h>
#include <cstdint>

#define NH 12
#define HD 64
#define NSEQ 2048
#define CDIM 768
#define NB 2

// ---------------------------------------------------------------------------
// Kernel 1a: Q,K = x @ qkv_w[0:1536]^T with f64 accumulation.
// 128x64 tile, 8x4 per thread, f64 LDS staging (cvt once at store).
// Outputs: Q64/K64 [bh][n][d] f64 (raw), Qs32 [bh][n][d] f32, Kt32 [bh][d][n] f32
// ---------------------------------------------------------------------------
__global__ __launch_bounds__(256, 4) void qkv_qk(const float* __restrict__ x,
                                                 const float* __restrict__ w,
                                                 double* __restrict__ Q64,
                                                 double* __restrict__ K64,
                                                 float* __restrict__ Qs32,
                                                 float* __restrict__ Kt32) {
    __shared__ double As[16][128];   // 16 KB
    __shared__ double Bs[16][64];    // 8 KB
    const int tid = threadIdx.x;
    const int bm = blockIdx.y * 128;      // M = 4096
    const int bn = blockIdx.x * 64;       // N = 1536 (Q,K only)
    const int alm = tid >> 1, alk = (tid & 1) * 8;
    const int blm = tid & 63, blk = (tid >> 6) * 4;
    const int tx = tid & 15, ty = tid >> 4;   // tx: 4 cols, ty: 8 rows

    double acc[8][4] = {};
    for (int k0 = 0; k0 < CDIM; k0 += 16) {
        float4 a0 = *reinterpret_cast<const float4*>(&x[(bm + alm) * CDIM + k0 + alk]);
        float4 a1 = *reinterpret_cast<const float4*>(&x[(bm + alm) * CDIM + k0 + alk + 4]);
        float4 b0 = *reinterpret_cast<const float4*>(&w[(bn + blm) * CDIM + k0 + blk]);
        __syncthreads();
        As[alk + 0][alm] = (double)a0.x; As[alk + 1][alm] = (double)a0.y;
        As[alk + 2][alm] = (double)a0.z; As[alk + 3][alm] = (double)a0.w;
        As[alk + 4][alm] = (double)a1.x; As[alk + 5][alm] = (double)a1.y;
        As[alk + 6][alm] = (double)a1.z; As[alk + 7][alm] = (double)a1.w;
        Bs[blk + 0][blm] = (double)b0.x; Bs[blk + 1][blm] = (double)b0.y;
        Bs[blk + 2][blm] = (double)b0.z; Bs[blk + 3][blm] = (double)b0.w;
        __syncthreads();
#pragma unroll
        for (int k = 0; k < 16; ++k) {
            double ad[8], bd[4];
#pragma unroll
            for (int i = 0; i < 8; ++i) ad[i] = As[k][ty * 8 + i];
#pragma unroll
            for (int j = 0; j < 4; ++j) bd[j] = Bs[k][tx * 4 + j];
#pragma unroll
            for (int i = 0; i < 8; ++i)
#pragma unroll
                for (int j = 0; j < 4; ++j) acc[i][j] = fma(ad[i], bd[j], acc[i][j]);
        }
        __syncthreads();
    }
    const bool isQ = bn < CDIM;
    const int hh = (isQ ? bn : bn - CDIM) >> 6;
    const int b  = bm >> 11;
    const int bh = b * NH + hh;
#pragma unroll
    for (int i = 0; i < 8; ++i) {
        const int n = (bm + ty * 8 + i) & (NSEQ - 1);
        const size_t base = ((size_t)bh * NSEQ + n) * HD + tx * 4;
        if (isQ) {
            double2 d01; d01.x = acc[i][0]; d01.y = acc[i][1];
            double2 d23; d23.x = acc[i][2]; d23.y = acc[i][3];
            *reinterpret_cast<double2*>(&Q64[base]) = d01;
            *reinterpret_cast<double2*>(&Q64[base + 2]) = d23;
            *reinterpret_cast<float4*>(&Qs32[base]) =
                make_float4((float)acc[i][0], (float)acc[i][1], (float)acc[i][2], (float)acc[i][3]);
        } else {
            double2 d01; d01.x = acc[i][0]; d01.y = acc[i][1];
            double2 d23; d23.x = acc[i][2]; d23.y = acc[i][3];
            *reinterpret_cast<double2*>(&K64[base]) = d01;
            *reinterpret_cast<double2*>(&K64[base + 2]) = d23;
#pragma unroll
            for (int j = 0; j < 4; ++j)
                Kt32[((size_t)bh * HD + tx * 4 + j) * NSEQ + n] = (float)acc[i][j];
        }
    }
}

// ---------------------------------------------------------------------------
// Kernel 1b: V = x @ qkv_w[1536:2304]^T, f32 (64x64 tile, 4x4/thread)
// ---------------------------------------------------------------------------
__global__ __launch_bounds__(256) void qkv_v(const float* __restrict__ x,
                                             const float* __restrict__ wv,
                                             float* __restrict__ V) {
    __shared__ float As[16][64];
    __shared__ float Bs[16][64];
    const int tid = threadIdx.x;
    const int bm = blockIdx.y * 64;
    const int bn = blockIdx.x * 64;    // 0..767 relative to V block
    const int lm = tid >> 2;
    const int lk = (tid & 3) << 2;
    const int tx = tid & 15, ty = tid >> 4;

    float acc[4][4] = {};
    for (int k0 = 0; k0 < CDIM; k0 += 16) {
        float4 av = *reinterpret_cast<const float4*>(&x[(bm + lm) * CDIM + k0 + lk]);
        float4 bv = *reinterpret_cast<const float4*>(&wv[(bn + lm) * CDIM + k0 + lk]);
        __syncthreads();
        As[lk + 0][lm] = av.x; As[lk + 1][lm] = av.y; As[lk + 2][lm] = av.z; As[lk + 3][lm] = av.w;
        Bs[lk + 0][lm] = bv.x; Bs[lk + 1][lm] = bv.y; Bs[lk + 2][lm] = bv.z; Bs[lk + 3][lm] = bv.w;
        __syncthreads();
#pragma unroll
        for (int k = 0; k < 16; ++k) {
            float4 a4 = *reinterpret_cast<const float4*>(&As[k][ty * 4]);
            float4 b4 = *reinterpret_cast<const float4*>(&Bs[k][tx * 4]);
            float aa[4] = {a4.x, a4.y, a4.z, a4.w};
            float bb[4] = {b4.x, b4.y, b4.z, b4.w};
#pragma unroll
            for (int i = 0; i < 4; ++i)
#pragma unroll
                for (int j = 0; j < 4; ++j) acc[i][j] = fmaf(aa[i], bb[j], acc[i][j]);
        }
    }
    const int hh = bn >> 6;
    const int b  = bm >> 11;
#pragma unroll
    for (int i = 0; i < 4; ++i) {
        const int n = (bm + ty * 4 + i) & (NSEQ - 1);
        *reinterpret_cast<float4*>(&V[(((size_t)b * NH + hh) * NSEQ + n) * HD + tx * 4]) =
            make_float4(acc[i][0], acc[i][1], acc[i][2], acc[i][3]);
    }
}

// ---------------------------------------------------------------------------
// Kernel 2: f32 bulk scores -> u16-key candidates (ballot select) ->
// group-coalesced f64 rescore -> packed 128-wide bitonic -> exact f64
// softmax/top-p -> sparse PV
// block = 512 threads (8 waves), 8 rows of one (b,h); wave w owns row w
// ---------------------------------------------------------------------------
__device__ inline unsigned long long d2key(double f) {
    unsigned long long u = (unsigned long long)__double_as_longlong(f);
    return u ^ (unsigned long long)(((long long)u >> 63) | (long long)0x8000000000000000ull);
}
__device__ inline double key2d(unsigned long long k) {
    unsigned long long mask = ((long long)k < 0) ? 0x8000000000000000ull : 0xFFFFFFFFFFFFFFFFull;
    return __longlong_as_double((long long)(k ^ mask));
}
__device__ inline unsigned kp(float a, float b) {
    unsigned ua = __float_as_uint(a);
    ua ^= (unsigned)(((int)ua >> 31) | 0x80000000);
    unsigned ub = __float_as_uint(b);
    ub ^= (unsigned)(((int)ub >> 31) | 0x80000000);
    return (ua >> 16) | (ub & 0xFFFF0000u);
}

__global__ __launch_bounds__(512, 6) void attn_kernel(const double* __restrict__ Q64,
                                                      const double* __restrict__ K64,
                                                      const float* __restrict__ Qs32,
                                                      const float* __restrict__ Kt32,
                                                      const float* __restrict__ V,
                                                      const float* __restrict__ temp,
                                                      const int* __restrict__ topk_p,
                                                      float* __restrict__ AO) {
    __shared__ unsigned short sk[8][NSEQ];   // 32 KB u16 proxy keys (row r's 4KB
                                             // later reused as 1KB packed-key scratch)
    __shared__ int cand[8][128];

    const int tid  = threadIdx.x;              // 0..511
    const int bh   = blockIdx.x >> 8;
    const int g0   = (blockIdx.x & 255) << 3;
    const int lane = tid & 63;
    const int wv   = tid >> 6;

    const double scale = 0.125 * (double)temp[0];
    const float sc32 = (float)scale;
    int TK = *topk_p;
    if (TK > 64) TK = 64;
    if (TK < 1)  TK = 1;

    // ---- phase 2: raw f32 dots; thread owns 4 cols for all 8 rows.
    // q read via block-uniform scalar loads (SGPR), no LDS.
    const float* __restrict__ kb = Kt32 + (size_t)bh * HD * NSEQ;
    const float* __restrict__ qp = Qs32 + ((size_t)bh * NSEQ + g0) * HD;  // qp[r*64+d]
    const int m0 = tid * 4;
    float acc[8][4] = {};
#pragma unroll 4
    for (int d = 0; d < HD; ++d) {
        float4 k4 = *reinterpret_cast<const float4*>(&kb[(size_t)d * NSEQ + m0]);
        float kv[4] = {k4.x, k4.y, k4.z, k4.w};
#pragma unroll
        for (int r8 = 0; r8 < 8; ++r8) {
            float qv = qp[r8 * HD + d];
#pragma unroll
            for (int c = 0; c < 4; ++c) acc[r8][c] = fmaf(qv, kv[c], acc[r8][c]);
        }
    }
#pragma unroll
    for (int r8 = 0; r8 < 8; ++r8) {
        uint2 pkv;
        pkv.x = kp(acc[r8][0] * sc32, acc[r8][1] * sc32);
        pkv.y = kp(acc[r8][2] * sc32, acc[r8][3] * sc32);
        *reinterpret_cast<uint2*>(&sk[r8][m0]) = pkv;
    }
    __syncthreads();

    // ---- phase 3: wave wv owns row wv
    const int r = wv;
    const int row = g0 + r;

    int k32[32];
#pragma unroll
    for (int i = 0; i < 32; ++i) k32[i] = sk[r][i * 64 + lane];

    // wave max of keys
    int mx = k32[0];
#pragma unroll
    for (int i = 1; i < 32; ++i) mx = max(mx, k32[i]);
#pragma unroll
    for (int off = 32; off > 0; off >>= 1) mx = max(mx, __shfl_xor(mx, off));

    // windowed binary search on u16 keys via ballot+popc (count lands in SGPR):
    // largest lo with count(>=lo) >= TK, stop once that count <= 96
    int lo0 = mx > 1024 ? mx - 1024 : 0;
    int c0 = 0;
#pragma unroll
    for (int i = 0; i < 32; ++i) c0 += (int)__popcll(__ballot(k32[i] >= lo0));
    int lo, hi, clo;
    if (c0 >= TK) { lo = lo0; clo = c0; hi = mx; }
    else          { lo = 0;   clo = NSEQ; hi = lo0 - 1; }
    while (lo < hi && clo > 96) {
        int mid = lo + ((hi - lo + 1) >> 1);
        int c = 0;
#pragma unroll
        for (int i = 0; i < 32; ++i) c += (int)__popcll(__ballot(k32[i] >= mid));
        if (c >= TK) { lo = mid; clo = c; } else hi = mid - 1;
    }
    int thr = lo >= 2 ? lo - 2 : 0;   // margin covers f32-dot + trunc error

    // ballot-based compaction of candidate column indices (deterministic order)
    const unsigned long long lmask = (1ull << lane) - 1ull;
    int base = 0;
#pragma unroll
    for (int i = 0; i < 32; ++i) {
        bool pred = k32[i] >= thr;
        unsigned long long bal = __ballot(pred);
        if (pred) {
            int slot = base + (int)__popcll(bal & lmask);
            if (slot < 128) cand[r][slot] = i * 64 + lane;
        }
        base += (int)__popcll(bal);
    }
    int ncand = min(base, 128);
    asm volatile("s_waitcnt lgkmcnt(0)" ::: "memory");

    // ---- group-coalesced f64 rescore: 8 groups x 8 lanes; group g owns slots
    // 16g..16g+15 (staggered start per group to spread LDS write banks);
    // lane sl reads k[m][sl*8..sl*8+8) (contiguous 512B per group)
    const int gidx = lane >> 3;
    const int sl   = lane & 7;
    const double* __restrict__ qrow = Q64 + ((size_t)bh * NSEQ + row) * HD;
    double qd[8];
#pragma unroll
    for (int j = 0; j < 8; ++j) qd[j] = qrow[sl * 8 + j];

    unsigned long long* pkr = reinterpret_cast<unsigned long long*>(&sk[r][0]);
    const double* __restrict__ kbase = K64 + (size_t)bh * NSEQ * HD;
#pragma unroll 2
    for (int jj = 0; jj < 16; ++jj) {
        const int j = (jj + gidx) & 15;          // stagger: distinct banks per group
        const int s = gidx * 16 + j;
        const int ms = cand[r][min(s, ncand - 1)];
        const double* __restrict__ kp8 = kbase + (size_t)ms * HD + sl * 8;
        double a = 0.0;
#pragma unroll
        for (int d = 0; d < 8; ++d) a = fma(qd[d], kp8[d], a);
        // 8-lane tree reduction (deterministic f64 order)
        a += __shfl_xor(a, 1);
        a += __shfl_xor(a, 2);
        a += __shfl_xor(a, 4);
        a *= scale;
        unsigned long long pkv = (s < ncand)
            ? ((d2key(a) & ~2047ull) | (unsigned long long)(2047 - ms)) : 0ull;
        if (sl == (jj & 7)) pkr[s] = pkv;
    }
    asm volatile("s_waitcnt lgkmcnt(0)" ::: "memory");
    unsigned long long pk1 = pkr[lane];
    unsigned long long pk2 = pkr[64 + lane];

    // 128-wide bitonic (2/lane), ascending in t = ~pk  == descending by pk
    unsigned long long t0 = ~pk1, t1 = ~pk2;
#pragma unroll
    for (int k = 2; k <= 64; k <<= 1) {
#pragma unroll
        for (int j = k >> 1; j > 0; j >>= 1) {
            {
                unsigned long long ot = __shfl_xor(t0, j);
                bool dir = (lane & k) != 0;
                bool lower = (lane & j) == 0;
                bool takeMin = (lower != dir);
                bool less = t0 < ot;
                t0 = (takeMin == less) ? t0 : ot;
            }
            {
                unsigned long long ot = __shfl_xor(t1, j);
                bool dir = (k == 64) ? true : ((lane & k) != 0);
                bool lower = (lane & j) == 0;
                bool takeMin = (lower != dir);
                bool less = t1 < ot;
                t1 = (takeMin == less) ? t1 : ot;
            }
        }
    }
    {   // k=128, j=64 cross-slot exchange
        unsigned long long na = (t1 < t0) ? t1 : t0;
        unsigned long long nb = (t1 < t0) ? t0 : t1;
        t0 = na; t1 = nb;
    }
#pragma unroll
    for (int j = 32; j > 0; j >>= 1) {
        {
            unsigned long long ot = __shfl_xor(t0, j);
            bool lower = (lane & j) == 0;
            bool less = t0 < ot;
            t0 = (lower == less) ? t0 : ot;
        }
        {
            unsigned long long ot = __shfl_xor(t1, j);
            bool lower = (lane & j) == 0;
            bool less = t1 < ot;
            t1 = (lower == less) ? t1 : ot;
        }
    }
    // lane l holds l-th largest candidate
    unsigned long long kk = ~t0;
    int mi = 2047 - (int)(kk & 2047ull);
    bool valid = lane < TK;
    double a = valid ? key2d(kk & ~2047ull) : 0.0;
    double amax = __shfl(a, 0);
    double s = valid ? exp(a - amax) : 0.0;

    double ps = s;
#pragma unroll
    for (int off = 1; off < 64; off <<= 1) {
        double tt = __shfl_up(ps, off);
        if (lane >= off) ps += tt;
    }
    double S = __shfl(ps, 63);
    double cumprev = (ps - s) / S;
    bool keep = valid && ((lane == 0) || (cumprev <= 0.9));
    double sk2 = keep ? s : 0.0;
    double S2 = sk2;
#pragma unroll
    for (int off = 32; off > 0; off >>= 1) S2 += __shfl_xor(S2, off);
    float p = (float)(keep ? (s / S2) : 0.0);

    unsigned long long bal = __ballot(keep);
    int nk = __popcll(bal);

    const float* __restrict__ vb = V + (size_t)bh * NSEQ * HD;
    float o = 0.f;
    for (int i = 0; i < nk; ++i) {
        float pi = __shfl(p, i);
        int midx = __shfl(mi, i);
        o = fmaf(pi, vb[(size_t)midx * HD + lane], o);
    }
    const int b = bh / NH, hh = bh % NH;
    AO[((size_t)b * NSEQ + row) * CDIM + hh * HD + lane] = o;
}

// ---------------------------------------------------------------------------
// Kernel 3: out = AO @ proj_w^T + proj_b   (f32, 128x64 tile, 8x4/thread)
// ---------------------------------------------------------------------------
__global__ __launch_bounds__(256) void proj_gemm(const float* __restrict__ A,
                                                 const float* __restrict__ w,
                                                 const float* __restrict__ bias,
                                                 float* __restrict__ out) {
    __shared__ float As[16][128];
    __shared__ float Bs[16][64];
    const int tid = threadIdx.x;
    const int bm = blockIdx.y * 128;
    const int bn = blockIdx.x * 64;
    const int alm = tid >> 1, alk = (tid & 1) * 8;
    const int blm = tid & 63, blk = (tid >> 6) * 4;
    const int tx = tid & 15, ty = tid >> 4;

    float acc[8][4] = {};
    for (int k0 = 0; k0 < CDIM; k0 += 16) {
        float4 a0 = *reinterpret_cast<const float4*>(&A[(bm + alm) * CDIM + k0 + alk]);
        float4 a1 = *reinterpret_cast<const float4*>(&A[(bm + alm) * CDIM + k0 + alk + 4]);
        float4 b0 = *reinterpret_cast<const float4*>(&w[(bn + blm) * CDIM + k0 + blk]);
        __syncthreads();
        As[alk + 0][alm] = a0.x; As[alk + 1][alm] = a0.y;
        As[alk + 2][alm] = a0.z; As[alk + 3][alm] = a0.w;
        As[alk + 4][alm] = a1.x; As[alk + 5][alm] = a1.y;
        As[alk + 6][alm] = a1.z; As[alk + 7][alm] = a1.w;
        Bs[blk + 0][blm] = b0.x; Bs[blk + 1][blm] = b0.y;
        Bs[blk + 2][blm] = b0.z; Bs[blk + 3][blm] = b0.w;
        __syncthreads();
#pragma unroll
        for (int k = 0; k < 16; ++k) {
            float4 af0 = *reinterpret_cast<const float4*>(&As[k][ty * 8]);
            float4 af1 = *reinterpret_cast<const float4*>(&As[k][ty * 8 + 4]);
            float4 bf  = *reinterpret_cast<const float4*>(&Bs[k][tx * 4]);
            float aa[8] = {af0.x, af0.y, af0.z, af0.w, af1.x, af1.y, af1.z, af1.w};
            float bb[4] = {bf.x, bf.y, bf.z, bf.w};
#pragma unroll
            for (int i = 0; i < 8; ++i)
#pragma unroll
                for (int j = 0; j < 4; ++j) acc[i][j] = fmaf(aa[i], bb[j], acc[i][j]);
        }
        __syncthreads();
    }
    float4 bv = *reinterpret_cast<const float4*>(&bias[bn + tx * 4]);
#pragma unroll
    for (int i = 0; i < 8; ++i) {
        int rr = bm + ty * 8 + i;
        float4 v4 = make_float4(acc[i][0] + bv.x, acc[i][1] + bv.y,
                                acc[i][2] + bv.z, acc[i][3] + bv.w);
        *reinterpret_cast<float4*>(&out[(size_t)rr * CDIM + bn + tx * 4]) = v4;
    }
}

// ---------------------------------------------------------------------------
extern "C" void kernel_launch(void* const* d_in, const int* in_sizes, int n_in,
                              void* d_out, int out_size, void* d_ws, size_t ws_size,
                              hipStream_t stream) {
    const float* x      = (const float*)d_in[0];
    const float* qkv_w  = (const float*)d_in[1];
    const float* proj_w = (const float*)d_in[2];
    const float* proj_b = (const float*)d_in[3];
    const float* temp   = (const float*)d_in[4];
    const int*   topk   = (const int*)d_in[5];
    float* out = (float*)d_out;

    const size_t HSZ = (size_t)NB * NH * NSEQ * HD;  // 3,145,728 elements
    double* Q64  = (double*)d_ws;           // 24 MB
    double* K64  = Q64 + HSZ;               // 24 MB
    float*  Qs32 = (float*)(K64 + HSZ);     // 12 MB
    float*  Kt32 = Qs32 + HSZ;              // 12 MB
    float*  V    = Kt32 + HSZ;              // 12 MB
    float*  AO   = V + HSZ;                 // 12 MB  -> 96 MB total

    qkv_qk<<<dim3(24, 32), 256, 0, stream>>>(x, qkv_w, Q64, K64, Qs32, Kt32);
    qkv_v<<<dim3(12, 64), 256, 0, stream>>>(x, qkv_w + (size_t)2 * CDIM * CDIM, V);
    attn_kernel<<<dim3(NB * NH * (NSEQ / 8)), 512, 0, stream>>>(Q64, K64, Qs32, Kt32, V, temp, topk, AO);
    proj_gemm<<<dim3(12, 32), 256, 0, stream>>>(AO, proj_w, proj_b, out);
}